// Round 20
// baseline (840.685 us; speedup 1.0000x reference)
//
#include <hip/hip_runtime.h>
#include <hip/hip_bf16.h>
#include <math.h>

#define H_ 1024
#define NH_ 16
#define HD_ 64
#define I_ 4096
#define E_ 8
#define B_ 2
#define S_ 2048
#define T_ 4096

#define MAXSLOTS 9216   // 2*T + 8*128 pad
#define MAXTILES 72     // MAXSLOTS/128

typedef __attribute__((ext_vector_type(8))) short short8v;
typedef __attribute__((ext_vector_type(4))) float f32x4;

#define GLOAD16(g, l) __builtin_amdgcn_global_load_lds((const __attribute__((address_space(1))) void*)(g), (__attribute__((address_space(3))) void*)(l), 16, 0, 0)

static __device__ inline unsigned short f2bf(float x) {
    __hip_bfloat16 h = __float2bfloat16(x);
    unsigned short u;
    __builtin_memcpy(&u, &h, 2);
    return u;
}
static __device__ inline float bf2f(unsigned short u) {
    __hip_bfloat16 h;
    __builtin_memcpy(&h, &u, 2);
    return __bfloat162float(h);
}

// exact-gelu via A&S 7.1.26 erf approximation (max abs err 1.5e-7 << bf16 rounding)
static __device__ inline float gelu_fast(float x) {
    float z  = x * 0.70710678118654752f;
    float az = fabsf(z);
    float t  = __builtin_amdgcn_rcpf(fmaf(0.3275911f, az, 1.f));
    float p  = fmaf(1.061405429f, t, -1.453152027f);
    p = fmaf(p, t, 1.421413741f);
    p = fmaf(p, t, -0.284496736f);
    p = fmaf(p, t, 0.254829592f);
    p = p * t;
    float e = __expf(-az*az);
    float er = 1.f - p*e;
    er = (z < 0.f) ? -er : er;
    return 0.5f * x * (1.f + er);
}

// ---------------- prep: split x (blocks <4096) + transpose+split Wq/Wk/Wv/Wd ----------------
__global__ __launch_bounds__(256) void prep_inputs(
    const float* __restrict__ x,
    const float* __restrict__ Wq, const float* __restrict__ Wk,
    const float* __restrict__ Wv, const float* __restrict__ Wd,
    __hip_bfloat16* __restrict__ xa_hi, __hip_bfloat16* __restrict__ xa_lo,
    __hip_bfloat16* __restrict__ wqkv_h, __hip_bfloat16* __restrict__ wqkv_l,
    __hip_bfloat16* __restrict__ wd_h, __hip_bfloat16* __restrict__ wd_l)
{
    __shared__ float t[64][65];
    const int bid = blockIdx.x;
    const int tid = threadIdx.x;
    if (bid < 4096) {
        int i = bid * 256 + tid;
        float4 v = ((const float4*)x)[i];
        unsigned short h0 = f2bf(v.x), h1 = f2bf(v.y), h2 = f2bf(v.z), h3 = f2bf(v.w);
        unsigned short l0 = f2bf(v.x - bf2f(h0)), l1 = f2bf(v.y - bf2f(h1));
        unsigned short l2 = f2bf(v.z - bf2f(h2)), l3 = f2bf(v.w - bf2f(h3));
        uint2 ph = make_uint2((unsigned)h0 | ((unsigned)h1 << 16), (unsigned)h2 | ((unsigned)h3 << 16));
        uint2 pl = make_uint2((unsigned)l0 | ((unsigned)l1 << 16), (unsigned)l2 | ((unsigned)l3 << 16));
        *(uint2*)((char*)xa_hi + (size_t)i*8) = ph;
        *(uint2*)((char*)xa_lo + (size_t)i*8) = pl;
        return;
    }
    int tt = bid - 4096;                 // 1024 blocks: 16 x 16 x 4
    int bx = tt & 15, by = (tt >> 4) & 15, z = tt >> 8;
    const float* in = (z==0) ? Wq : (z==1) ? Wk : (z==2) ? Wv : Wd;
    __hip_bfloat16* oh = (z<3) ? (wqkv_h + (size_t)z*1024*1024) : wd_h;
    __hip_bfloat16* ol = (z<3) ? (wqkv_l + (size_t)z*1024*1024) : wd_l;
    int k0 = by*64, n0 = bx*64;
    #pragma unroll
    for (int it=0; it<4; ++it) {
        int lin = it*256 + tid;
        int r = lin >> 4, c4 = (lin & 15) << 2;
        float4 v = *(const float4*)&in[(size_t)(k0+r)*1024 + n0 + c4];
        t[r][c4] = v.x; t[r][c4+1] = v.y; t[r][c4+2] = v.z; t[r][c4+3] = v.w;
    }
    __syncthreads();
    #pragma unroll
    for (int it=0; it<4; ++it) {
        int lin = it*256 + tid;
        int r = lin >> 4, c4 = (lin & 15) << 2;
        float v0 = t[c4][r], v1 = t[c4+1][r], v2 = t[c4+2][r], v3 = t[c4+3][r];
        ushort4 hh, ll;
        hh.x = f2bf(v0); hh.y = f2bf(v1); hh.z = f2bf(v2); hh.w = f2bf(v3);
        ll.x = f2bf(v0 - bf2f(hh.x)); ll.y = f2bf(v1 - bf2f(hh.y));
        ll.z = f2bf(v2 - bf2f(hh.z)); ll.w = f2bf(v3 - bf2f(hh.w));
        size_t o = (size_t)(n0+r)*1024 + k0 + c4;
        *(ushort4*)&oh[o] = hh;
        *(ushort4*)&ol[o] = ll;
    }
}

// ---------------- transpose + f32->bf16 (standalone, PE path only) ----------------
__global__ __launch_bounds__(256) void transpose_bf16(
    const float* __restrict__ in, __hip_bfloat16* __restrict__ outp, int K, int N)
{
    __shared__ float t[64][65];
    size_t eoff = (size_t)blockIdx.z * (size_t)K * (size_t)N;
    int k0 = blockIdx.y*64, n0 = blockIdx.x*64;
    int tid = threadIdx.x;
    #pragma unroll
    for (int it=0; it<4; ++it) {
        int lin = it*256 + tid;
        int r = lin >> 4, c4 = (lin & 15) << 2;
        float4 v = *(const float4*)&in[eoff + (size_t)(k0+r)*N + n0 + c4];
        t[r][c4] = v.x; t[r][c4+1] = v.y; t[r][c4+2] = v.z; t[r][c4+3] = v.w;
    }
    __syncthreads();
    #pragma unroll
    for (int it=0; it<4; ++it) {
        int lin = it*256 + tid;
        int r = lin >> 4, c4 = (lin & 15) << 2;
        ushort4 o;
        o.x = f2bf(t[c4][r]);   o.y = f2bf(t[c4+1][r]);
        o.z = f2bf(t[c4+2][r]); o.w = f2bf(t[c4+3][r]);
        *(ushort4*)&outp[eoff + (size_t)(n0+r)*K + k0 + c4] = o;
    }
}

// ---------------- FUSED: Wd bf16x3 GEMM (blocks <256) + moe_out/misc zero (rest) ----------------
__global__ __launch_bounds__(256, 2) void wd_gemm_zero(
    const __hip_bfloat16* __restrict__ Ah, const __hip_bfloat16* __restrict__ Al,
    const __hip_bfloat16* __restrict__ Bh, const __hip_bfloat16* __restrict__ Bl,
    float* __restrict__ C, const float* __restrict__ bias,
    float* __restrict__ moe_out, float* __restrict__ misc16)
{
    const int bid = blockIdx.x;
    const int tid = threadIdx.x;
    if (bid >= 256) {
        int z = bid - 256;              // 4096 blocks
        ((float4*)moe_out)[z*256 + tid] = (float4){0.f,0.f,0.f,0.f};
        if (z == 0 && tid < 16) misc16[tid] = 0.f;
        return;
    }
    const int N = 1024, K = 1024;
    const int w = tid >> 6, lane = tid & 63;
    const int xcd = bid & 7, ix = bid >> 3;
    const int by = xcd*4 + ix / 8;
    const int bx = ix % 8;

    __shared__ __align__(16) char smem[65536];
    const int AH = 0, AL = 16384, BH = 32768, BL = 49152;

    const int laneg = lane >> 3;
    const int k2sw = ((lane & 7) ^ laneg) << 4;
    const int l15 = lane & 15, l4 = lane >> 4;
    const int wr = w >> 1, wc = w & 1;

    f32x4 acc[4][4];
    #pragma unroll
    for (int m=0;m<4;m++)
        #pragma unroll
        for (int n=0;n<4;n++) acc[m][n] = (f32x4){0.f,0.f,0.f,0.f};

    for (int k0 = 0; k0 < K; k0 += 64) {
        __syncthreads();
        #pragma unroll
        for (int qq=0;qq<4;qq++) {
            int arow = by*128 + (w*4+qq)*8 + laneg;
            int brow = bx*128 + (w*4+qq)*8 + laneg;
            size_t aoff = ((size_t)arow*K + k0)*2 + k2sw;
            size_t boff = ((size_t)brow*K + k0)*2 + k2sw;
            GLOAD16((const char*)Ah + aoff, smem + AH + (w*4+qq)*1024);
            GLOAD16((const char*)Al + aoff, smem + AL + (w*4+qq)*1024);
            GLOAD16((const char*)Bh + boff, smem + BH + (w*4+qq)*1024);
            GLOAD16((const char*)Bl + boff, smem + BL + (w*4+qq)*1024);
        }
        __syncthreads();

        short8v ahf[4][2], alf[4][2], bhf[4][2], blf[4][2];
        #pragma unroll
        for (int m=0;m<4;m++) {
            int row = wr*64 + m*16 + l15;
            int rb = row << 7, rsw = (row & 7) << 4;
            #pragma unroll
            for (int s=0;s<2;s++) {
                int off = rb + ((s*64 + (l4<<4)) ^ rsw);
                ahf[m][s] = *(const short8v*)(smem + AH + off);
                alf[m][s] = *(const short8v*)(smem + AL + off);
            }
        }
        #pragma unroll
        for (int n=0;n<4;n++) {
            int row = wc*64 + n*16 + l15;
            int rb = row << 7, rsw = (row & 7) << 4;
            #pragma unroll
            for (int s=0;s<2;s++) {
                int off = rb + ((s*64 + (l4<<4)) ^ rsw);
                bhf[n][s] = *(const short8v*)(smem + BH + off);
                blf[n][s] = *(const short8v*)(smem + BL + off);
            }
        }
        #pragma unroll
        for (int m=0;m<4;m++)
            #pragma unroll
            for (int n=0;n<4;n++)
                #pragma unroll
                for (int s=0;s<2;s++) {
                    acc[m][n] = __builtin_amdgcn_mfma_f32_16x16x32_bf16(ahf[m][s], bhf[n][s], acc[m][n], 0, 0, 0);
                    acc[m][n] = __builtin_amdgcn_mfma_f32_16x16x32_bf16(ahf[m][s], blf[n][s], acc[m][n], 0, 0, 0);
                    acc[m][n] = __builtin_amdgcn_mfma_f32_16x16x32_bf16(alf[m][s], bhf[n][s], acc[m][n], 0, 0, 0);
                }
    }

    #pragma unroll
    for (int m=0;m<4;m++)
        #pragma unroll
        for (int j=0;j<4;j++) {
            int orow = by*128 + wr*64 + m*16 + l4*4 + j;
            #pragma unroll
            for (int n=0;n<4;n++) {
                int ocol = bx*128 + wc*64 + n*16 + l15;
                C[(size_t)orow*N + ocol] = acc[m][n][j] + bias[ocol];
            }
        }
}

// ---------------- FUSED: QKV bf16x3 GEMM + token-major RoPE/split epilogue (blocks <768)
//                + W1/W2 transpose (blocks >=768, FULL path only) ----------------
// Q/K outputs: token-major [T][1024] bf16 hi/lo (row-major => fully coalesced stores).
// V output: f32 to qkv buffer cols 2048..3071 (transposed+split later).
__global__ __launch_bounds__(256, 2) void fused_qkv_w12(
    const __hip_bfloat16* __restrict__ Ah, const __hip_bfloat16* __restrict__ Al,
    const __hip_bfloat16* __restrict__ Bh, const __hip_bfloat16* __restrict__ Bl,
    float* __restrict__ C,
    __hip_bfloat16* __restrict__ at_qh, __hip_bfloat16* __restrict__ at_ql,
    __hip_bfloat16* __restrict__ at_kh, __hip_bfloat16* __restrict__ at_kl,
    const float* __restrict__ W1, const float* __restrict__ W2,
    __hip_bfloat16* __restrict__ W1t, __hip_bfloat16* __restrict__ W2t)
{
    __shared__ __align__(16) char smem[65536];
    const int tid = threadIdx.x;
    const int bid = blockIdx.x;

    if (bid < 768) {
        const int N = 3072, K = 1024;
        const int w = tid >> 6, lane = tid & 63;
        const int xcd = bid & 7, ix = bid >> 3;
        const int by = xcd*4 + ix / 24;
        const int bx = ix % 24;
        const int AH = 0, AL = 16384, BH = 32768, BL = 49152;
        const int laneg = lane >> 3;
        const int k2sw = ((lane & 7) ^ laneg) << 4;
        const int l15 = lane & 15, l4 = lane >> 4;
        const int wr = w >> 1, wc = w & 1;

        f32x4 acc[4][4];
        #pragma unroll
        for (int m=0;m<4;m++)
            #pragma unroll
            for (int n=0;n<4;n++) acc[m][n] = (f32x4){0.f,0.f,0.f,0.f};

        for (int k0 = 0; k0 < K; k0 += 64) {
            __syncthreads();
            #pragma unroll
            for (int qq=0;qq<4;qq++) {
                int arow = by*128 + (w*4+qq)*8 + laneg;
                int brow = bx*128 + (w*4+qq)*8 + laneg;
                size_t aoff = ((size_t)arow*K + k0)*2 + k2sw;
                size_t boff = ((size_t)brow*K + k0)*2 + k2sw;
                GLOAD16((const char*)Ah + aoff, smem + AH + (w*4+qq)*1024);
                GLOAD16((const char*)Al + aoff, smem + AL + (w*4+qq)*1024);
                GLOAD16((const char*)Bh + boff, smem + BH + (w*4+qq)*1024);
                GLOAD16((const char*)Bl + boff, smem + BL + (w*4+qq)*1024);
            }
            __syncthreads();

            short8v ahf[4][2], alf[4][2], bhf[4][2], blf[4][2];
            #pragma unroll
            for (int m=0;m<4;m++) {
                int row = wr*64 + m*16 + l15;
                int rb = row << 7, rsw = (row & 7) << 4;
                #pragma unroll
                for (int s=0;s<2;s++) {
                    int off = rb + ((s*64 + (l4<<4)) ^ rsw);
                    ahf[m][s] = *(const short8v*)(smem + AH + off);
                    alf[m][s] = *(const short8v*)(smem + AL + off);
                }
            }
            #pragma unroll
            for (int n=0;n<4;n++) {
                int row = wc*64 + n*16 + l15;
                int rb = row << 7, rsw = (row & 7) << 4;
                #pragma unroll
                for (int s=0;s<2;s++) {
                    int off = rb + ((s*64 + (l4<<4)) ^ rsw);
                    bhf[n][s] = *(const short8v*)(smem + BH + off);
                    blf[n][s] = *(const short8v*)(smem + BL + off);
                }
            }
            #pragma unroll
            for (int m=0;m<4;m++)
                #pragma unroll
                for (int n=0;n<4;n++)
                    #pragma unroll
                    for (int s=0;s<2;s++) {
                        acc[m][n] = __builtin_amdgcn_mfma_f32_16x16x32_bf16(ahf[m][s], bhf[n][s], acc[m][n], 0, 0, 0);
                        acc[m][n] = __builtin_amdgcn_mfma_f32_16x16x32_bf16(ahf[m][s], blf[n][s], acc[m][n], 0, 0, 0);
                        acc[m][n] = __builtin_amdgcn_mfma_f32_16x16x32_bf16(alf[m][s], bhf[n][s], acc[m][n], 0, 0, 0);
                    }
        }

        if (bx >= 16) {
            // V columns: plain f32 store
            #pragma unroll
            for (int m=0;m<4;m++)
                #pragma unroll
                for (int j=0;j<4;j++) {
                    int orow = by*128 + wr*64 + m*16 + l4*4 + j;
                    #pragma unroll
                    for (int n=0;n<4;n++) {
                        int ocol = bx*128 + wc*64 + n*16 + l15;
                        C[(size_t)orow*N + ocol] = acc[m][n][j];
                    }
                }
        } else {
            // Q (bx<8) / K: RoPE in-register, token-major bf16 hi/lo stores.
            // Pairs: col i (n=0,1) with col i+32 (n+2). Stores cover head*64..+63 contiguous.
            const bool isQ = bx < 8;
            const int colbase = bx*128 + wc*64;        // Q: 0..960, K: 1024..1984
            const int hcol = colbase & 1023;           // head*64 within the 1024-col array
            __hip_bfloat16* oh = isQ ? at_qh : at_kh;
            __hip_bfloat16* ol = isQ ? at_ql : at_kl;
            const float sc = isQ ? 0.125f : 1.f;
            float inv0 = exp2f((float)(l15)      * (-13.287712379549449f / 32.f));
            float inv1 = exp2f((float)(16 + l15) * (-13.287712379549449f / 32.f));
            #pragma unroll
            for (int m=0;m<4;m++)
                #pragma unroll
                for (int j=0;j<4;j++) {
                    int orow = by*128 + wr*64 + m*16 + l4*4 + j;   // token index
                    int pos = orow & (S_-1);
                    size_t obase = (size_t)orow*1024 + hcol;
                    #pragma unroll
                    for (int n=0;n<2;n++) {
                        int i = n*16 + l15;
                        float v1 = acc[m][n][j];
                        float v2 = acc[m][n+2][j];
                        float ang = (float)pos * (n ? inv1 : inv0);
                        float c = cosf(ang), s = sinf(ang);
                        float o1 = (v1*c - v2*s) * sc;
                        float o2 = (v2*c + v1*s) * sc;
                        unsigned short h1 = f2bf(o1), h2 = f2bf(o2);
                        unsigned short L1 = f2bf(o1 - bf2f(h1)), L2 = f2bf(o2 - bf2f(h2));
                        oh[obase + i]      = *(__hip_bfloat16*)&h1;
                        oh[obase + i + 32] = *(__hip_bfloat16*)&h2;
                        ol[obase + i]      = *(__hip_bfloat16*)&L1;
                        ol[obase + i + 32] = *(__hip_bfloat16*)&L2;
                    }
                }
        }
        return;
    }

    // ---- transpose path (FULL only) ----
    int t = bid - 768;
    const float* src;
    __hip_bfloat16* dst;
    int K, N;
    if (t < 8192) { src = W1; dst = W1t; K = 1024; N = 4096; }
    else          { t -= 8192; src = W2; dst = W2t; K = 4096; N = 1024; }
    const int nb_n = N >> 6;
    int bx = t % nb_n;
    int rest = t / nb_n;
    int by = rest % (K >> 6);
    int bz = rest / (K >> 6);
    size_t eoff = (size_t)bz * (size_t)K * (size_t)N;
    int k0 = by*64, n0 = bx*64;
    float (*tt)[65] = (float(*)[65])smem;
    #pragma unroll
    for (int it=0; it<4; ++it) {
        int lin = it*256 + tid;
        int r = lin >> 4, c4 = (lin & 15) << 2;
        float4 v = *(const float4*)&src[eoff + (size_t)(k0+r)*N + n0 + c4];
        tt[r][c4] = v.x; tt[r][c4+1] = v.y; tt[r][c4+2] = v.z; tt[r][c4+3] = v.w;
    }
    __syncthreads();
    #pragma unroll
    for (int it=0; it<4; ++it) {
        int lin = it*256 + tid;
        int r = lin >> 4, c4 = (lin & 15) << 2;
        ushort4 o;
        o.x = f2bf(tt[c4][r]);   o.y = f2bf(tt[c4+1][r]);
        o.z = f2bf(tt[c4+2][r]); o.w = f2bf(tt[c4+3][r]);
        *(ushort4*)&dst[eoff + (size_t)(n0+r)*K + k0 + c4] = o;
    }
}

// ---------------- MFMA MoE GEMM ----------------
template<int MODE, bool PE>
__global__ __launch_bounds__(256) void moe_mfma(
    const __hip_bfloat16* __restrict__ A,
    const __hip_bfloat16* __restrict__ Bt,
    __hip_bfloat16* __restrict__ y1,
    float* __restrict__ moe_out,
    const int* __restrict__ slot_token,
    const float* __restrict__ slot_w,
    const int* __restrict__ tile_expert,
    const int* __restrict__ cnt_ptr,
    const int* __restrict__ base_ptr,
    int N, int K, int nbx)
{
    const int tid = threadIdx.x;
    const int w = tid >> 6, lane = tid & 63;

    int bx, slot0, y1row0;
    const __hip_bfloat16* Bp;
    if (PE) {
        bx = blockIdx.x;
        int tloc = blockIdx.y;
        if ((tloc << 7) >= *cnt_ptr) return;
        slot0 = *base_ptr + (tloc << 7);
        y1row0 = tloc << 7;
        Bp = Bt;
    } else {
        const int wg = blockIdx.x;
        const int xcd = wg & 7, ix = wg >> 3;
        const int byc = (int)(gridDim.x >> 3) / nbx;
        int gt = xcd*byc + ix % byc;                   // bx-major: tile varies fastest
        bx = ix / byc;
        if (gt >= *cnt_ptr) return;
        int e = tile_expert[gt];
        Bp = Bt + (size_t)e * (size_t)K * (size_t)N;
        slot0 = gt << 7;
        y1row0 = gt << 7;
    }

    __shared__ __align__(16) char smem[32768];

    const int laneg = lane >> 3;
    const int k2sw = ((lane & 7) ^ laneg) << 4;

    int tokq[4];
    if (MODE == 2) {
        #pragma unroll
        for (int qq=0;qq<4;qq++) {
            int t0 = slot_token[slot0 + (w*4+qq)*8 + laneg];
            tokq[qq] = t0 < 0 ? 0 : t0;
        }
    }

    f32x4 acc[4][4];
    #pragma unroll
    for (int m=0;m<4;m++)
        #pragma unroll
        for (int n=0;n<4;n++) acc[m][n] = (f32x4){0.f,0.f,0.f,0.f};

    const int l15 = lane & 15;
    const int l4  = lane >> 4;
    const int wr = w >> 1, wc = w & 1;

    for (int k0 = 0; k0 < K; k0 += 64) {
        __syncthreads();
        #pragma unroll
        for (int qq=0;qq<4;qq++) {
            const char* ga;
            if (MODE == 2) {
                ga = (const char*)A + (((size_t)tokq[qq])*K + k0)*2 + k2sw;
            } else {
                int row = y1row0 + (w*4+qq)*8 + laneg;
                ga = (const char*)A + ((size_t)row*K + k0)*2 + k2sw;
            }
            GLOAD16(ga, smem + (w*4+qq)*1024);
        }
        #pragma unroll
        for (int qq=0;qq<4;qq++) {
            int row = bx*128 + (w*4+qq)*8 + laneg;
            const char* gb = (const char*)Bp + ((size_t)row*K + k0)*2 + k2sw;
            GLOAD16(gb, smem + 16384 + (w*4+qq)*1024);
        }
        __syncthreads();

        short8v a_frag[4][2], b_frag[4][2];
        #pragma unroll
        for (int m=0;m<4;m++) {
            int row = wr*64 + m*16 + l15;
            int rb = row << 7;
            #pragma unroll
            for (int s=0;s<2;s++) {
                int off = rb + ((s*64 + (l4<<4)) ^ ((row&7)<<4));
                a_frag[m][s] = *(const short8v*)(smem + off);
            }
        }
        #pragma unroll
        for (int n=0;n<4;n++) {
            int row = wc*64 + n*16 + l15;
            int rb = row << 7;
            #pragma unroll
            for (int s=0;s<2;s++) {
                int off = rb + ((s*64 + (l4<<4)) ^ ((row&7)<<4));
                b_frag[n][s] = *(const short8v*)(smem + 16384 + off);
            }
        }
        #pragma unroll
        for (int m=0;m<4;m++)
            #pragma unroll
            for (int n=0;n<4;n++) {
                acc[m][n] = __builtin_amdgcn_mfma_f32_16x16x32_bf16(a_frag[m][0], b_frag[n][0], acc[m][n], 0, 0, 0);
                acc[m][n] = __builtin_amdgcn_mfma_f32_16x16x32_bf16(a_frag[m][1], b_frag[n][1], acc[m][n], 0, 0, 0);
            }
    }

    if (MODE == 3) {
        #pragma unroll
        for (int m=0;m<4;m++) {
            #pragma unroll
            for (int j=0;j<4;j++) {
                int orow = wr*64 + m*16 + l4*4 + j;
                int slot = slot0 + orow;
                int tok = slot_token[slot];
                if (tok < 0) continue;
                float sw = slot_w[slot];
                #pragma unroll
                for (int n=0;n<4;n++) {
                    int ocol = bx*128 + wc*64 + n*16 + l15;
                    atomicAdd(&moe_out[(size_t)tok*H_ + ocol], sw * acc[m][n][j]);
                }
            }
        }
    } else {
        __syncthreads();
        #pragma unroll
        for (int m=0;m<4;m++)
            #pragma unroll
            for (int j=0;j<4;j++) {
                int orow = wr*64 + m*16 + l4*4 + j;
                #pragma unroll
                for (int n=0;n<4;n++) {
                    int ocol = wc*64 + n*16 + l15;
                    unsigned short g = f2bf(gelu_fast(acc[m][n][j]));
                    *(unsigned short*)(smem + orow*256 + ocol*2) = g;
                }
            }
        __syncthreads();
        #pragma unroll
        for (int s=0;s<8;s++) {
            int row = w*32 + s*4 + l4;
            short8v v = *(const short8v*)(smem + row*256 + l15*16);
            *(short8v*)((char*)y1 + ((size_t)(y1row0 + row)*N + bx*128 + l15*8)*2) = v;
        }
    }
}

// ---------------- V transpose + split (1024 blocks) ----------------
__global__ __launch_bounds__(256) void v_transpose_split(
    const float* __restrict__ qkv,
    __hip_bfloat16* __restrict__ vth, __hip_bfloat16* __restrict__ vtl)
{
    __shared__ float t[64][65];
    const int tt = blockIdx.x;      // 1024 blocks: 32 x 16 x 2
    const int tid = threadIdx.x;
    const int s0 = (tt & 31)*64;
    const int hn = (tt >> 5) & 15;
    const int b  = tt >> 9;
    #pragma unroll
    for (int it=0; it<4; ++it) {
        int lin = it*256 + tid;
        int r = lin >> 4, c4 = (lin & 15) << 2;
        float4 vv = *(const float4*)&qkv[(size_t)(b*S_ + s0 + r)*3072 + 2048 + hn*64 + c4];
        t[r][c4] = vv.x; t[r][c4+1] = vv.y; t[r][c4+2] = vv.z; t[r][c4+3] = vv.w;
    }
    __syncthreads();
    size_t obase = (size_t)(b*NH_ + hn)*64*S_;
    #pragma unroll
    for (int it=0; it<4; ++it) {
        int lin = it*256 + tid;
        int d = lin >> 4, c4 = (lin & 15) << 2;
        float v0 = t[c4][d], v1 = t[c4+1][d], v2 = t[c4+2][d], v3 = t[c4+3][d];
        ushort4 hh, ll;
        hh.x = f2bf(v0); hh.y = f2bf(v1); hh.z = f2bf(v2); hh.w = f2bf(v3);
        ll.x = f2bf(v0 - bf2f(hh.x)); ll.y = f2bf(v1 - bf2f(hh.y));
        ll.z = f2bf(v2 - bf2f(hh.z)); ll.w = f2bf(v3 - bf2f(hh.w));
        size_t o = obase + (size_t)d*S_ + s0 + c4;
        *(ushort4*)&vth[o] = hh;
        *(ushort4*)&vtl[o] = ll;
    }
}

// ---------------- MFMA attention: bf16x3, XCD-swizzled, no-max softmax, 32KB LDS,
// 128 q-rows/block. Q/K are TOKEN-MAJOR [T][1024] (head slice = 128B/row, stride 2048B). ----------------
__global__ __launch_bounds__(256) void attn_mfma(
    const __hip_bfloat16* __restrict__ qh, const __hip_bfloat16* __restrict__ ql,
    const __hip_bfloat16* __restrict__ kh, const __hip_bfloat16* __restrict__ kl,
    const __hip_bfloat16* __restrict__ vth, const __hip_bfloat16* __restrict__ vtl,
    __hip_bfloat16* __restrict__ ctx_hi, __hip_bfloat16* __restrict__ ctx_lo)
{
    const int wg = blockIdx.x;          // 512 blocks
    const int xcd = wg & 7;
    const int ix = wg >> 3;             // 0..63
    const int head = xcd*4 + (ix >> 4); // 4 heads per XCD
    const int qt = ix & 15;             // 16 tiles of 128 q-rows
    const int b = head >> 4, hn = head & 15;

    const int tid = threadIdx.x;
    const int w = tid >> 6, lane = tid & 63;
    const int l15 = lane & 15, l4 = lane >> 4;
    const int laneg = lane >> 3;
    const int k2sw = ((lane & 7) ^ laneg) << 4;

    __shared__ __align__(16) char smem[32768];
    const int KHo = 0, KLo = 8192, VHo = 16384, VLo = 24576;
    const int PHo = 0, PLo = 8192;

    const size_t tok0  = (size_t)b*S_;          // token base for this batch
    const size_t hcol2 = (size_t)hn*64*2;       // byte offset of head's 64-col slice
    const size_t vbase = (size_t)head*64*S_;

    short8v qhf[2][2], qlf[2][2];
    #pragma unroll
    for (int m=0;m<2;m++) {
        #pragma unroll
        for (int qq=0;qq<2;qq++) {
            int c = w*2 + qq;
            int row = qt*128 + m*64 + c*8 + laneg;
            size_t off = (tok0 + row)*2048 + hcol2 + k2sw;
            GLOAD16((const char*)qh + off, smem + KHo + c*1024);
            GLOAD16((const char*)ql + off, smem + KLo + c*1024);
        }
        __syncthreads();
        {
            int row = w*16 + l15;
            int rsw = (row & 7) << 4;
            #pragma unroll
            for (int s=0;s<2;s++) {
                int off = row*128 + ((s*64 + l4*16) ^ rsw);
                qhf[m][s] = *(const short8v*)(smem + KHo + off);
                qlf[m][s] = *(const short8v*)(smem + KLo + off);
            }
        }
        __syncthreads();
    }

    f32x4 acc[2][4];
    #pragma unroll
    for (int m=0;m<2;m++)
        #pragma unroll
        for (int db=0;db<4;db++) acc[m][db] = (f32x4){0.f,0.f,0.f,0.f};
    float lrun[2][4] = {{0.f,0.f,0.f,0.f},{0.f,0.f,0.f,0.f}};

    for (int kt=0; kt<S_/64; ++kt) {
        #pragma unroll
        for (int qq=0;qq<2;qq++) {
            int c = w*2 + qq;
            int r8 = c*8 + laneg;
            size_t koff = (tok0 + kt*64 + r8)*2048 + hcol2 + k2sw;
            GLOAD16((const char*)kh + koff, smem + KHo + c*1024);
            GLOAD16((const char*)kl + koff, smem + KLo + c*1024);
            size_t voff = (vbase + (size_t)r8*S_ + kt*64)*2 + k2sw;
            GLOAD16((const char*)vth + voff, smem + VHo + c*1024);
            GLOAD16((const char*)vtl + voff, smem + VLo + c*1024);
        }
        __syncthreads();

        f32x4 s_acc[2][4];
        #pragma unroll
        for (int cb=0;cb<4;cb++) {
            s_acc[0][cb] = (f32x4){0.f,0.f,0.f,0.f};
            s_acc[1][cb] = (f32x4){0.f,0.f,0.f,0.f};
            int row = cb*16 + l15;
            int rsw = (row & 7) << 4;
            #pragma unroll
            for (int s=0;s<2;s++) {
                int off = row*128 + ((s*64 + l4*16) ^ rsw);
                short8v khf = *(const short8v*)(smem + KHo + off);
                short8v klf = *(const short8v*)(smem + KLo + off);
                s_acc[0][cb] = __builtin_amdgcn_mfma_f32_16x16x32_bf16(qhf[0][s], khf, s_acc[0][cb], 0, 0, 0);
                s_acc[0][cb] = __builtin_amdgcn_mfma_f32_16x16x32_bf16(qhf[0][s], klf, s_acc[0][cb], 0, 0, 0);
                s_acc[0][cb] = __builtin_amdgcn_mfma_f32_16x16x32_bf16(qlf[0][s], khf, s_acc[0][cb], 0, 0, 0);
                s_acc[1][cb] = __builtin_amdgcn_mfma_f32_16x16x32_bf16(qhf[1][s], khf, s_acc[1][cb], 0, 0, 0);
                s_acc[1][cb] = __builtin_amdgcn_mfma_f32_16x16x32_bf16(qhf[1][s], klf, s_acc[1][cb], 0, 0, 0);
                s_acc[1][cb] = __builtin_amdgcn_mfma_f32_16x16x32_bf16(qlf[1][s], khf, s_acc[1][cb], 0, 0, 0);
            }
        }
        __syncthreads();

        #pragma unroll
        for (int m=0;m<2;m++) {
            #pragma unroll
            for (int cb=0;cb<4;cb++)
                #pragma unroll
                for (int j=0;j<4;j++) {
                    float p = __expf(s_acc[m][cb][j]);
                    lrun[m][j] += p;
                    int prow = w*16 + l4*4 + j;
                    unsigned short hh = f2bf(p);
                    unsigned short ll = f2bf(p - bf2f(hh));
                    int off = prow*128 + (((cb*16 + l15)*2) ^ ((prow&7)<<4));
                    *(unsigned short*)(smem + PHo + off) = hh;
                    *(unsigned short*)(smem + PLo + off) = ll;
                }
            asm volatile("s_waitcnt lgkmcnt(0)" ::: "memory");
            __builtin_amdgcn_sched_barrier(0);

            short8v pah[2], pal[2];
            {
                int row = w*16 + l15;
                int rsw = (row & 7) << 4;
                #pragma unroll
                for (int s=0;s<2;s++) {
                    int off = row*128 + ((s*64 + l4*16) ^ rsw);
                    pah[s] = *(const short8v*)(smem + PHo + off);
                    pal[s] = *(const short8v*)(smem + PLo + off);
                }
            }
            #pragma unroll
            for (int db=0;db<4;db++) {
                int row = db*16 + l15;
                int rsw = (row & 7) << 4;
                #pragma unroll
                for (int s=0;s<2;s++) {
                    int off = row*128 + ((s*64 + l4*16) ^ rsw);
                    short8v vhf = *(const short8v*)(smem + VHo + off);
                    short8v vlf = *(const short8v*)(smem + VLo + off);
                    acc[m][db] = __builtin_amdgcn_mfma_f32_16x16x32_bf16(pah[s], vhf, acc[m][db], 0, 0, 0);
                    acc[m][db] = __builtin_amdgcn_mfma_f32_16x16x32_bf16(pah[s], vlf, acc[m][db], 0, 0, 0);
                    acc[m][db] = __builtin_amdgcn_mfma_f32_16x16x32_bf16(pal[s], vhf, acc[m][db], 0, 0, 0);
                }
            }
            __builtin_amdgcn_sched_barrier(0);
        }
        __syncthreads();
    }

    #pragma unroll
    for (int m=0;m<2;m++) {
        #pragma unroll
        for (int j=0;j<4;j++) {
            float s = lrun[m][j];
            #pragma unroll
            for (int mk=8;mk;mk>>=1) s += __shfl_xor(s, mk);
            lrun[m][j] = s;
        }
        #pragma unroll
        for (int db=0;db<4;db++)
            #pragma unroll
            for (int j=0;j<4;j++) {
                int qrow = qt*128 + m*64 + w*16 + l4*4 + j;
                float o = acc[m][db][j] / lrun[m][j];
                unsigned short hh = f2bf(o);
                unsigned short ll = f2bf(o - bf2f(hh));
                size_t oidx = (size_t)(b*S_ + qrow)*H_ + hn*64 + db*16 + l15;
                ctx_hi[oidx] = *(__hip_bfloat16*)&hh;
                ctx_lo[oidx] = *(__hip_bfloat16*)&ll;
            }
    }
}

// ---------------- layernorm (residual fused, optional bf16 out) ----------------
__global__ __launch_bounds__(256) void ln_kernel(
    const float* __restrict__ a, const float* __restrict__ res,
    const float* __restrict__ g, const float* __restrict__ beta,
    float* __restrict__ out, __hip_bfloat16* __restrict__ outb)
{
    int row = blockIdx.x, tid = threadIdx.x;
    const float4 va = ((const float4*)(a + (size_t)row*H_))[tid];
    const float4 vr = ((const float4*)(res + (size_t)row*H_))[tid];
    float x0=va.x+vr.x, x1=va.y+vr.y, x2=va.z+vr.z, x3=va.w+vr.w;
    float s  = x0+x1+x2+x3;
    float ss = x0*x0 + x1*x1 + x2*x2 + x3*x3;
    #pragma unroll
    for (int off=32; off; off>>=1) { s += __shfl_xor(s, off); ss += __shfl_xor(ss, off); }
    __shared__ float red[8];
    if ((tid&63)==0) { red[tid>>6]=s; red[4+(tid>>6)]=ss; }
    __syncthreads();
    if (tid==0) { red[0]=red[0]+red[1]+red[2]+red[3]; red[4]=red[4]+red[5]+red[6]+red[7]; }
    __syncthreads();
    float mu  = red[0] * (1.f/H_);
    float var = red[4] * (1.f/H_) - mu*mu;
    float rs = rsqrtf(fmaxf(var, 0.f) + 1e-12f);
    const float4 vg = ((const float4*)g)[tid];
    const float4 vb = ((const float4*)beta)[tid];
    float4 vo;
    vo.x = (x0-mu)*rs*vg.x + vb.x;
    vo.y = (x1-mu)*rs*vg.y + vb.y;
    vo.z = (x2-mu)*rs*vg.z + vb.z;
    vo.w = (x3-mu)*rs*vg.w + vb.w;
    ((float4*)(out + (size_t)row*H_))[tid] = vo;
    if (outb) {
        unsigned int p0 = (unsigned)f2bf(vo.x) | ((unsigned)f2bf(vo.y) << 16);
        unsigned int p1 = (unsigned)f2bf(vo.z) | ((unsigned)f2bf(vo.w) << 16);
        ((uint2*)(outb + (size_t)row*H_))[tid] = make_uint2(p0, p1);
    }
}

// ---------------- router: 64 blocks x 64 tokens, register-accumulated stats ----------------
__global__ __launch_bounds__(256) void router_kernel(
    const float* __restrict__ hs, const float* __restrict__ Wg,
    int* __restrict__ tok_e, float* __restrict__ tok_w,
    int* __restrict__ counts, float* __restrict__ P_sum)
{
    const int w = threadIdx.x >> 6, lane = threadIdx.x & 63;
    float psum[E_];
    int cnt[E_];
    #pragma unroll
    for (int e=0;e<E_;e++){ psum[e]=0.f; cnt[e]=0; }

    for (int it=0; it<16; ++it) {
        int t = blockIdx.x*64 + it*4 + w;
        const float* row = hs + (size_t)t * H_;
        float acc[E_];
        #pragma unroll
        for (int e=0;e<E_;e++) acc[e]=0.f;
        for (int i16=0; i16<16; ++i16) {
            int i = i16*64 + lane;
            float xv = row[i];
            const float* wg = Wg + (size_t)i*E_;
            #pragma unroll
            for (int e=0;e<E_;e++) acc[e] = fmaf(xv, wg[e], acc[e]);
        }
        #pragma unroll
        for (int e=0;e<E_;e++) {
            float vv = acc[e];
            #pragma unroll
            for (int off=32; off; off>>=1) vv += __shfl_xor(vv, off);
            acc[e] = vv;
        }
        float mx = acc[0];
        #pragma unroll
        for (int e=1;e<E_;e++) mx = fmaxf(mx, acc[e]);
        float p[E_], se=0.f;
        #pragma unroll
        for (int e=0;e<E_;e++){ p[e] = __expf(acc[e]-mx); se += p[e]; }
        float isv = 1.f/se;
        #pragma unroll
        for (int e=0;e<E_;e++){ p[e]*=isv; psum[e] += p[e]; }
        int e1=0;
        #pragma unroll
        for (int e=1;e<E_;e++) if (p[e] > p[e1]) e1=e;
        int e2 = (e1==0)?1:0;
        #pragma unroll
        for (int e=0;e<E_;e++) if (e!=e1 && p[e] > p[e2]) e2=e;
        #pragma unroll
        for (int e=0;e<E_;e++) cnt[e] += (e==e1?1:0) + (e==e2?1:0);
        if (lane==0) {
            float w1=p[e1], w2=p[e2], si=1.f/(w1+w2);
            tok_e[t*2]=e1; tok_e[t*2+1]=e2;
            tok_w[t*2]=w1*si; tok_w[t*2+1]=w2*si;
        }
    }
    if (lane==0) {
        #pragma unroll
        for (int e=0;e<E_;e++) {
            atomicAdd(&P_sum[e], psum[e]);
            atomicAdd(&counts[e], cnt[e]);
        }
    }
}

__global__ void router_finalize(
    const int* __restrict__ counts, const float* __restrict__ P_sum,
    int* __restrict__ base, int* __restrict__ cursor,
    int* __restrict__ cnt_pad, int* __restrict__ ntiles,
    int* __restrict__ slot_token, int* __restrict__ tile_expert,
    float* __restrict__ aux_out)
{
    __shared__ int sbase[E_+1];
    if (threadIdx.x == 0) {
        int bacc = 0;
        float aux = 0.f;
        for (int e=0;e<E_;e++) {
            sbase[e] = bacc; base[e] = bacc;
            int cp = (counts[e] + 127) & ~127;
            cnt_pad[e] = cp;
            bacc += cp;
            cursor[e] = 0;
            aux += ((float)counts[e]/(float)T_) * (P_sum[e]/(float)T_);
        }
        sbase[E_] = bacc;
        *ntiles = bacc >> 7;
        *aux_out = (float)E_ * aux;
    }
    __syncthreads();
    for (int sIdx = (int)threadIdx.x; sIdx < MAXSLOTS; sIdx += (int)blockDim.x)
        slot_token[sIdx] = -1;
    for (int tt = (int)threadIdx.x; tt < MAXTILES; tt += (int)blockDim.x) {
        int s = tt*128;
        int e = E_-1;
        for (int qe=0; qe<E_; ++qe) if (s < sbase[qe+1]) { e = qe; break; }
        tile_expert[tt] = e;
    }
}

__global__ void scatter_slots(
    const int* __restrict__ tok_e, const float* __restrict__ tok_w,
    const int* __restrict__ base, int* __restrict__ cursor,
    int* __restrict__ slot_token, float* __restrict__ slot_w)
{
    int t = blockIdx.x*blockDim.x + threadIdx.x;
    if (t >= T_) return;
    #pragma unroll
    for (int j=0;j<2;j++) {
        int e = tok_e[t*2+j];
        int pos = atomicAdd(&cursor[e], 1);
        int s = base[e] + pos;
        slot_token[s] = t;
        slot_w[s] = tok_w[t*2+j];
    }
}

extern "C" void kernel_launch(void* const* d_in, const int* in_sizes, int n_in,
                              void* d_out, int out_size, void* d_ws, size_t ws_size,
                              hipStream_t stream)
{
    const float* x    = (const float*)d_in[0];
    const float* Wq   = (const float*)d_in[1];
    const float* Wk   = (const float*)d_in[2];
    const float* Wv   = (const float*)d_in[3];
    const float* Wd   = (const float*)d_in[4];
    const float* bd   = (const float*)d_in[5];
    const float* ln1g = (const float*)d_in[6];
    const float* ln1b = (const float*)d_in[7];
    const float* Wg   = (const float*)d_in[8];
    const float* W1   = (const float*)d_in[9];
    const float* W2   = (const float*)d_in[10];
    const float* ln2g = (const float*)d_in[11];
    const float* ln2b = (const float*)d_in[12];
    float* out = (float*)d_out;

    float* f0 = (float*)d_ws;
    const size_t M1 = 1u << 20;
    float* qkv      = f0;
    float* attn_out = f0 + 12*M1;
    float* hs       = f0;
    float* moe_out  = f0 + 4*M1;
    __hip_bfloat16* hs_b = (__hip_bfloat16*)(f0 + 16*M1);

    float* misc = f0 + 18*M1;
    int*   misc_i = (int*)misc;
    int*   tok_e   = misc_i;
    float* tok_w   = misc + 8192;
    int*   slot_tok= misc_i + 16384;
    float* slot_w  = misc + 25600;
    int*   counts  = misc_i + 34816;
    float* P_sum   = misc + 34824;
    int*   cursor  = misc_i + 34832;
    int*   basep   = misc_i + 34840;
    int*   cnt_pad = misc_i + 34848;
    int*   ntiles  = misc_i + 34856;
    int*   tile_ex = misc_i + 34857;

    float* off_p = f0 + 18*M1 + 65536;
    __hip_bfloat16* xa_hi = (__hip_bfloat16*)(off_p);
    __hip_bfloat16* xa_lo = (__hip_bfloat16*)(off_p + 2*M1);
    __hip_bfloat16* at_qh = (__hip_bfloat16*)(off_p + 4*M1);
    __hip_bfloat16* at_ql = (__hip_bfloat16*)(off_p + 6*M1);
    __hip_bfloat16* at_kh = (__hip_bfloat16*)(off_p + 8*M1);
    __hip_bfloat16* at_kl = (__hip_bfloat16*)(off_p + 10*M1);
    __hip_bfloat16* at_vh = (__hip_bfloat16*)(off_p + 12*M1);
    __hip_bfloat16* at_vl = (__hip_bfloat16*)(off_p + 14*M1);
    __hip_bfloat16* wqkv_h = (__hip_bfloat16*)(off_p + 16*M1);
    __hip_bfloat16* wqkv_l = (__hip_bfloat16*)(off_p + 16*M1 + 3*(M1/2));
    __hip_bfloat16* wd_h = (__hip_bfloat16*)(off_p + 19*M1);
    __hip_bfloat16* wd_l = (__hip_bfloat16*)(off_p + 19*M1 + M1/2);

    const bool FULL = ws_size >= (size_t)300*1024*1024;
    // FULL layout: W1t @ +20M1 (16M1 span), W2t @ +36M1 (16M1 span).
    // y1F overlays off_p+0 .. +18.875M1 (xa + at_* + wqkv — all dead by MoE time).
    __hip_bfloat16* W1t = (__hip_bfloat16*)(off_p + 20*M1);
    __hip_bfloat16* W2t = (__hip_bfloat16*)(off_p + 36*M1);
    __hip_bfloat16* y1F = (__hip_bfloat16*)(off_p);
    float* wreg = off_p + 4*M1;   // PE path scratch

    dim3 blk(256);

    prep_inputs<<<dim3(5120), blk, 0, stream>>>(x, Wq, Wk, Wv, Wd, xa_hi, xa_lo, wqkv_h, wqkv_l, wd_h, wd_l);

    if (FULL) {
        fused_qkv_w12<<<dim3(768 + 8192 + 8192), blk, 0, stream>>>(
            xa_hi, xa_lo, wqkv_h, wqkv_l, qkv,
            at_qh, at_ql, at_kh, at_kl, W1, W2, W1t, W2t);
    } else {
        fused_qkv_w12<<<dim3(768), blk, 0, stream>>>(
            xa_hi, xa_lo, wqkv_h, wqkv_l, qkv,
            at_qh, at_ql, at_kh, at_kl, nullptr, nullptr, nullptr, nullptr);
    }

    v_transpose_split<<<dim3(1024), blk, 0, stream>>>(qkv, at_vh, at_vl);

    attn_mfma<<<dim3(B_*NH_*(S_/128)), blk, 0, stream>>>(at_qh, at_ql, at_kh, at_kl, at_vh, at_vl, xa_hi, xa_lo);

    // attn_out = ctx@Wd + bd, fused with moe_out/misc zeroing
    wd_gemm_zero<<<dim3(256 + 4096), blk, 0, stream>>>(xa_hi, xa_lo, wd_h, wd_l, attn_out, bd, moe_out, misc + 34816);

    ln_kernel<<<T_, blk, 0, stream>>>(attn_out, x, ln1g, ln1b, hs, hs_b);

    router_kernel<<<T_/64, blk, 0, stream>>>(hs, Wg, tok_e, tok_w, counts, P_sum);
    router_finalize<<<1, blk, 0, stream>>>(counts, P_sum, basep, cursor, cnt_pad, ntiles,
                                           slot_tok, tile_ex, out + (size_t)T_*H_);
    scatter_slots<<<T_/256, blk, 0, stream>>>(tok_e, tok_w, basep, cursor, slot_tok, slot_w);

    if (FULL) {
        moe_mfma<2,false><<<dim3(MAXTILES*32), blk, 0, stream>>>(
            hs_b, W1t, y1F, nullptr, slot_tok, slot_w, tile_ex, ntiles, nullptr, I_, H_, 32);
        moe_mfma<3,false><<<dim3(MAXTILES*8), blk, 0, stream>>>(
            y1F, W2t, nullptr, moe_out, slot_tok, slot_w, tile_ex, ntiles, nullptr, H_, I_, 8);
    } else {
        __hip_bfloat16* w1t = (__hip_bfloat16*)wreg;
        __hip_bfloat16* w2t = (__hip_bfloat16*)(wreg + 2*M1);
        __hip_bfloat16* y1  = (__hip_bfloat16*)(wreg + 4*M1);
        for (int e=0; e<E_; ++e) {
            transpose_bf16<<<dim3(I_/64, H_/64, 1), blk, 0, stream>>>(W1 + (size_t)e*H_*I_, w1t, H_, I_);
            moe_mfma<2,true><<<dim3(I_/128, 32), blk, 0, stream>>>(
                hs_b, w1t, y1, nullptr, slot_tok, slot_w, nullptr, cnt_pad+e, basep+e, I_, H_, 0);
            transpose_bf16<<<dim3(H_/64, I_/64, 1), blk, 0, stream>>>(W2 + (size_t)e*I_*H_, w2t, I_, H_);
            moe_mfma<3,true><<<dim3(H_/128, 32), blk, 0, stream>>>(
                y1, w2t, nullptr, moe_out, slot_tok, slot_w, nullptr, cnt_pad+e, basep+e, H_, I_, 0);
        }
    }

    ln_kernel<<<T_, blk, 0, stream>>>(moe_out, hs, ln2g, ln2b, out, nullptr);
}

// Round 21
// 693.269 us; speedup vs baseline: 1.2126x; 1.2126x over previous
//
#include <hip/hip_runtime.h>
#include <hip/hip_bf16.h>
#include <math.h>

#define H_ 1024
#define NH_ 16
#define HD_ 64
#define I_ 4096
#define E_ 8
#define B_ 2
#define S_ 2048
#define T_ 4096

#define MAXSLOTS 9216   // 2*T + 8*128 pad
#define MAXTILES 72     // MAXSLOTS/128

typedef __attribute__((ext_vector_type(8))) short short8v;
typedef __attribute__((ext_vector_type(4))) float f32x4;

#define GLOAD16(g, l) __builtin_amdgcn_global_load_lds((const __attribute__((address_space(1))) void*)(g), (__attribute__((address_space(3))) void*)(l), 16, 0, 0)

static __device__ inline unsigned short f2bf(float x) {
    __hip_bfloat16 h = __float2bfloat16(x);
    unsigned short u;
    __builtin_memcpy(&u, &h, 2);
    return u;
}
static __device__ inline float bf2f(unsigned short u) {
    __hip_bfloat16 h;
    __builtin_memcpy(&h, &u, 2);
    return __bfloat162float(h);
}

// exact-gelu via A&S 7.1.26 erf approximation (max abs err 1.5e-7 << bf16 rounding)
static __device__ inline float gelu_fast(float x) {
    float z  = x * 0.70710678118654752f;
    float az = fabsf(z);
    float t  = __builtin_amdgcn_rcpf(fmaf(0.3275911f, az, 1.f));
    float p  = fmaf(1.061405429f, t, -1.453152027f);
    p = fmaf(p, t, 1.421413741f);
    p = fmaf(p, t, -0.284496736f);
    p = fmaf(p, t, 0.254829592f);
    p = p * t;
    float e = __expf(-az*az);
    float er = 1.f - p*e;
    er = (z < 0.f) ? -er : er;
    return 0.5f * x * (1.f + er);
}

// ---------------- prep: split x (blocks <4096) + transpose+split Wq/Wk/Wv/Wd ----------------
__global__ __launch_bounds__(256) void prep_inputs(
    const float* __restrict__ x,
    const float* __restrict__ Wq, const float* __restrict__ Wk,
    const float* __restrict__ Wv, const float* __restrict__ Wd,
    __hip_bfloat16* __restrict__ xa_hi, __hip_bfloat16* __restrict__ xa_lo,
    __hip_bfloat16* __restrict__ wqkv_h, __hip_bfloat16* __restrict__ wqkv_l,
    __hip_bfloat16* __restrict__ wd_h, __hip_bfloat16* __restrict__ wd_l)
{
    __shared__ float t[64][65];
    const int bid = blockIdx.x;
    const int tid = threadIdx.x;
    if (bid < 4096) {
        int i = bid * 256 + tid;
        float4 v = ((const float4*)x)[i];
        unsigned short h0 = f2bf(v.x), h1 = f2bf(v.y), h2 = f2bf(v.z), h3 = f2bf(v.w);
        unsigned short l0 = f2bf(v.x - bf2f(h0)), l1 = f2bf(v.y - bf2f(h1));
        unsigned short l2 = f2bf(v.z - bf2f(h2)), l3 = f2bf(v.w - bf2f(h3));
        uint2 ph = make_uint2((unsigned)h0 | ((unsigned)h1 << 16), (unsigned)h2 | ((unsigned)h3 << 16));
        uint2 pl = make_uint2((unsigned)l0 | ((unsigned)l1 << 16), (unsigned)l2 | ((unsigned)l3 << 16));
        *(uint2*)((char*)xa_hi + (size_t)i*8) = ph;
        *(uint2*)((char*)xa_lo + (size_t)i*8) = pl;
        return;
    }
    int tt = bid - 4096;                 // 1024 blocks: 16 x 16 x 4
    int bx = tt & 15, by = (tt >> 4) & 15, z = tt >> 8;
    const float* in = (z==0) ? Wq : (z==1) ? Wk : (z==2) ? Wv : Wd;
    __hip_bfloat16* oh = (z<3) ? (wqkv_h + (size_t)z*1024*1024) : wd_h;
    __hip_bfloat16* ol = (z<3) ? (wqkv_l + (size_t)z*1024*1024) : wd_l;
    int k0 = by*64, n0 = bx*64;
    #pragma unroll
    for (int it=0; it<4; ++it) {
        int lin = it*256 + tid;
        int r = lin >> 4, c4 = (lin & 15) << 2;
        float4 v = *(const float4*)&in[(size_t)(k0+r)*1024 + n0 + c4];
        t[r][c4] = v.x; t[r][c4+1] = v.y; t[r][c4+2] = v.z; t[r][c4+3] = v.w;
    }
    __syncthreads();
    #pragma unroll
    for (int it=0; it<4; ++it) {
        int lin = it*256 + tid;
        int r = lin >> 4, c4 = (lin & 15) << 2;
        float v0 = t[c4][r], v1 = t[c4+1][r], v2 = t[c4+2][r], v3 = t[c4+3][r];
        ushort4 hh, ll;
        hh.x = f2bf(v0); hh.y = f2bf(v1); hh.z = f2bf(v2); hh.w = f2bf(v3);
        ll.x = f2bf(v0 - bf2f(hh.x)); ll.y = f2bf(v1 - bf2f(hh.y));
        ll.z = f2bf(v2 - bf2f(hh.z)); ll.w = f2bf(v3 - bf2f(hh.w));
        size_t o = (size_t)(n0+r)*1024 + k0 + c4;
        *(ushort4*)&oh[o] = hh;
        *(ushort4*)&ol[o] = ll;
    }
}

// ---------------- transpose + f32->bf16 (standalone, PE path only) ----------------
__global__ __launch_bounds__(256) void transpose_bf16(
    const float* __restrict__ in, __hip_bfloat16* __restrict__ outp, int K, int N)
{
    __shared__ float t[64][65];
    size_t eoff = (size_t)blockIdx.z * (size_t)K * (size_t)N;
    int k0 = blockIdx.y*64, n0 = blockIdx.x*64;
    int tid = threadIdx.x;
    #pragma unroll
    for (int it=0; it<4; ++it) {
        int lin = it*256 + tid;
        int r = lin >> 4, c4 = (lin & 15) << 2;
        float4 v = *(const float4*)&in[eoff + (size_t)(k0+r)*N + n0 + c4];
        t[r][c4] = v.x; t[r][c4+1] = v.y; t[r][c4+2] = v.z; t[r][c4+3] = v.w;
    }
    __syncthreads();
    #pragma unroll
    for (int it=0; it<4; ++it) {
        int lin = it*256 + tid;
        int r = lin >> 4, c4 = (lin & 15) << 2;
        ushort4 o;
        o.x = f2bf(t[c4][r]);   o.y = f2bf(t[c4+1][r]);
        o.z = f2bf(t[c4+2][r]); o.w = f2bf(t[c4+3][r]);
        *(ushort4*)&outp[eoff + (size_t)(n0+r)*K + k0 + c4] = o;
    }
}

// ---------------- FUSED: Wd bf16x3 GEMM (blocks <256) + moe_out/misc zero (rest) ----------------
__global__ __launch_bounds__(256, 2) void wd_gemm_zero(
    const __hip_bfloat16* __restrict__ Ah, const __hip_bfloat16* __restrict__ Al,
    const __hip_bfloat16* __restrict__ Bh, const __hip_bfloat16* __restrict__ Bl,
    float* __restrict__ C, const float* __restrict__ bias,
    float* __restrict__ moe_out, float* __restrict__ misc16)
{
    const int bid = blockIdx.x;
    const int tid = threadIdx.x;
    if (bid >= 256) {
        int z = bid - 256;              // 4096 blocks
        ((float4*)moe_out)[z*256 + tid] = (float4){0.f,0.f,0.f,0.f};
        if (z == 0 && tid < 16) misc16[tid] = 0.f;
        return;
    }
    const int N = 1024, K = 1024;
    const int w = tid >> 6, lane = tid & 63;
    const int xcd = bid & 7, ix = bid >> 3;
    const int by = xcd*4 + ix / 8;
    const int bx = ix % 8;

    __shared__ __align__(16) char smem[65536];
    const int AH = 0, AL = 16384, BH = 32768, BL = 49152;

    const int laneg = lane >> 3;
    const int k2sw = ((lane & 7) ^ laneg) << 4;
    const int l15 = lane & 15, l4 = lane >> 4;
    const int wr = w >> 1, wc = w & 1;

    f32x4 acc[4][4];
    #pragma unroll
    for (int m=0;m<4;m++)
        #pragma unroll
        for (int n=0;n<4;n++) acc[m][n] = (f32x4){0.f,0.f,0.f,0.f};

    for (int k0 = 0; k0 < K; k0 += 64) {
        __syncthreads();
        #pragma unroll
        for (int qq=0;qq<4;qq++) {
            int arow = by*128 + (w*4+qq)*8 + laneg;
            int brow = bx*128 + (w*4+qq)*8 + laneg;
            size_t aoff = ((size_t)arow*K + k0)*2 + k2sw;
            size_t boff = ((size_t)brow*K + k0)*2 + k2sw;
            GLOAD16((const char*)Ah + aoff, smem + AH + (w*4+qq)*1024);
            GLOAD16((const char*)Al + aoff, smem + AL + (w*4+qq)*1024);
            GLOAD16((const char*)Bh + boff, smem + BH + (w*4+qq)*1024);
            GLOAD16((const char*)Bl + boff, smem + BL + (w*4+qq)*1024);
        }
        __syncthreads();

        short8v ahf[4][2], alf[4][2], bhf[4][2], blf[4][2];
        #pragma unroll
        for (int m=0;m<4;m++) {
            int row = wr*64 + m*16 + l15;
            int rb = row << 7, rsw = (row & 7) << 4;
            #pragma unroll
            for (int s=0;s<2;s++) {
                int off = rb + ((s*64 + (l4<<4)) ^ rsw);
                ahf[m][s] = *(const short8v*)(smem + AH + off);
                alf[m][s] = *(const short8v*)(smem + AL + off);
            }
        }
        #pragma unroll
        for (int n=0;n<4;n++) {
            int row = wc*64 + n*16 + l15;
            int rb = row << 7, rsw = (row & 7) << 4;
            #pragma unroll
            for (int s=0;s<2;s++) {
                int off = rb + ((s*64 + (l4<<4)) ^ rsw);
                bhf[n][s] = *(const short8v*)(smem + BH + off);
                blf[n][s] = *(const short8v*)(smem + BL + off);
            }
        }
        #pragma unroll
        for (int m=0;m<4;m++)
            #pragma unroll
            for (int n=0;n<4;n++)
                #pragma unroll
                for (int s=0;s<2;s++) {
                    acc[m][n] = __builtin_amdgcn_mfma_f32_16x16x32_bf16(ahf[m][s], bhf[n][s], acc[m][n], 0, 0, 0);
                    acc[m][n] = __builtin_amdgcn_mfma_f32_16x16x32_bf16(ahf[m][s], blf[n][s], acc[m][n], 0, 0, 0);
                    acc[m][n] = __builtin_amdgcn_mfma_f32_16x16x32_bf16(alf[m][s], bhf[n][s], acc[m][n], 0, 0, 0);
                }
    }

    #pragma unroll
    for (int m=0;m<4;m++)
        #pragma unroll
        for (int j=0;j<4;j++) {
            int orow = by*128 + wr*64 + m*16 + l4*4 + j;
            #pragma unroll
            for (int n=0;n<4;n++) {
                int ocol = bx*128 + wc*64 + n*16 + l15;
                C[(size_t)orow*N + ocol] = acc[m][n][j] + bias[ocol];
            }
        }
}

// ---------------- FUSED: QKV bf16x3 GEMM (blocks <768) + W1/W2 transpose (rest) ----------------
__global__ __launch_bounds__(256, 2) void fused_qkv_w12(
    const __hip_bfloat16* __restrict__ Ah, const __hip_bfloat16* __restrict__ Al,
    const __hip_bfloat16* __restrict__ Bh, const __hip_bfloat16* __restrict__ Bl,
    float* __restrict__ C,
    const float* __restrict__ W1, const float* __restrict__ W2,
    __hip_bfloat16* __restrict__ W1t, __hip_bfloat16* __restrict__ W2t)
{
    __shared__ __align__(16) char smem[65536];
    const int tid = threadIdx.x;
    const int bid = blockIdx.x;

    if (bid < 768) {
        const int N = 3072, K = 1024;
        const int w = tid >> 6, lane = tid & 63;
        const int xcd = bid & 7, ix = bid >> 3;
        const int by = xcd*4 + ix / 24;
        const int bx = ix % 24;
        const int AH = 0, AL = 16384, BH = 32768, BL = 49152;
        const int laneg = lane >> 3;
        const int k2sw = ((lane & 7) ^ laneg) << 4;
        const int l15 = lane & 15, l4 = lane >> 4;
        const int wr = w >> 1, wc = w & 1;

        f32x4 acc[4][4];
        #pragma unroll
        for (int m=0;m<4;m++)
            #pragma unroll
            for (int n=0;n<4;n++) acc[m][n] = (f32x4){0.f,0.f,0.f,0.f};

        for (int k0 = 0; k0 < K; k0 += 64) {
            __syncthreads();
            #pragma unroll
            for (int qq=0;qq<4;qq++) {
                int arow = by*128 + (w*4+qq)*8 + laneg;
                int brow = bx*128 + (w*4+qq)*8 + laneg;
                size_t aoff = ((size_t)arow*K + k0)*2 + k2sw;
                size_t boff = ((size_t)brow*K + k0)*2 + k2sw;
                GLOAD16((const char*)Ah + aoff, smem + AH + (w*4+qq)*1024);
                GLOAD16((const char*)Al + aoff, smem + AL + (w*4+qq)*1024);
                GLOAD16((const char*)Bh + boff, smem + BH + (w*4+qq)*1024);
                GLOAD16((const char*)Bl + boff, smem + BL + (w*4+qq)*1024);
            }
            __syncthreads();

            short8v ahf[4][2], alf[4][2], bhf[4][2], blf[4][2];
            #pragma unroll
            for (int m=0;m<4;m++) {
                int row = wr*64 + m*16 + l15;
                int rb = row << 7, rsw = (row & 7) << 4;
                #pragma unroll
                for (int s=0;s<2;s++) {
                    int off = rb + ((s*64 + (l4<<4)) ^ rsw);
                    ahf[m][s] = *(const short8v*)(smem + AH + off);
                    alf[m][s] = *(const short8v*)(smem + AL + off);
                }
            }
            #pragma unroll
            for (int n=0;n<4;n++) {
                int row = wc*64 + n*16 + l15;
                int rb = row << 7, rsw = (row & 7) << 4;
                #pragma unroll
                for (int s=0;s<2;s++) {
                    int off = rb + ((s*64 + (l4<<4)) ^ rsw);
                    bhf[n][s] = *(const short8v*)(smem + BH + off);
                    blf[n][s] = *(const short8v*)(smem + BL + off);
                }
            }
            #pragma unroll
            for (int m=0;m<4;m++)
                #pragma unroll
                for (int n=0;n<4;n++)
                    #pragma unroll
                    for (int s=0;s<2;s++) {
                        acc[m][n] = __builtin_amdgcn_mfma_f32_16x16x32_bf16(ahf[m][s], bhf[n][s], acc[m][n], 0, 0, 0);
                        acc[m][n] = __builtin_amdgcn_mfma_f32_16x16x32_bf16(ahf[m][s], blf[n][s], acc[m][n], 0, 0, 0);
                        acc[m][n] = __builtin_amdgcn_mfma_f32_16x16x32_bf16(alf[m][s], bhf[n][s], acc[m][n], 0, 0, 0);
                    }
        }

        #pragma unroll
        for (int m=0;m<4;m++)
            #pragma unroll
            for (int j=0;j<4;j++) {
                int orow = by*128 + wr*64 + m*16 + l4*4 + j;
                #pragma unroll
                for (int n=0;n<4;n++) {
                    int ocol = bx*128 + wc*64 + n*16 + l15;
                    C[(size_t)orow*N + ocol] = acc[m][n][j];
                }
            }
        return;
    }

    // ---- transpose path ----
    int t = bid - 768;
    const float* src;
    __hip_bfloat16* dst;
    int K, N;
    if (t < 8192) { src = W1; dst = W1t; K = 1024; N = 4096; }
    else          { t -= 8192; src = W2; dst = W2t; K = 4096; N = 1024; }
    const int nb_n = N >> 6;
    int bx = t % nb_n;
    int rest = t / nb_n;
    int by = rest % (K >> 6);
    int bz = rest / (K >> 6);
    size_t eoff = (size_t)bz * (size_t)K * (size_t)N;
    int k0 = by*64, n0 = bx*64;
    float (*tt)[65] = (float(*)[65])smem;
    #pragma unroll
    for (int it=0; it<4; ++it) {
        int lin = it*256 + tid;
        int r = lin >> 4, c4 = (lin & 15) << 2;
        float4 v = *(const float4*)&src[eoff + (size_t)(k0+r)*N + n0 + c4];
        tt[r][c4] = v.x; tt[r][c4+1] = v.y; tt[r][c4+2] = v.z; tt[r][c4+3] = v.w;
    }
    __syncthreads();
    #pragma unroll
    for (int it=0; it<4; ++it) {
        int lin = it*256 + tid;
        int r = lin >> 4, c4 = (lin & 15) << 2;
        ushort4 o;
        o.x = f2bf(tt[c4][r]);   o.y = f2bf(tt[c4+1][r]);
        o.z = f2bf(tt[c4+2][r]); o.w = f2bf(tt[c4+3][r]);
        *(ushort4*)&dst[eoff + (size_t)(n0+r)*K + k0 + c4] = o;
    }
}

// ---------------- MFMA MoE GEMM ----------------
template<int MODE, bool PE>
__global__ __launch_bounds__(256) void moe_mfma(
    const __hip_bfloat16* __restrict__ A,
    const __hip_bfloat16* __restrict__ Bt,
    __hip_bfloat16* __restrict__ y1,
    float* __restrict__ moe_out,
    const int* __restrict__ slot_token,
    const float* __restrict__ slot_w,
    const int* __restrict__ tile_expert,
    const int* __restrict__ cnt_ptr,
    const int* __restrict__ base_ptr,
    int N, int K, int nbx)
{
    const int tid = threadIdx.x;
    const int w = tid >> 6, lane = tid & 63;

    int bx, slot0, y1row0;
    const __hip_bfloat16* Bp;
    if (PE) {
        bx = blockIdx.x;
        int tloc = blockIdx.y;
        if ((tloc << 7) >= *cnt_ptr) return;
        slot0 = *base_ptr + (tloc << 7);
        y1row0 = tloc << 7;
        Bp = Bt;
    } else {
        const int wg = blockIdx.x;
        const int xcd = wg & 7, ix = wg >> 3;
        const int byc = (int)(gridDim.x >> 3) / nbx;
        int gt = xcd*byc + ix % byc;                   // bx-major: tile varies fastest
        bx = ix / byc;
        if (gt >= *cnt_ptr) return;
        int e = tile_expert[gt];
        Bp = Bt + (size_t)e * (size_t)K * (size_t)N;
        slot0 = gt << 7;
        y1row0 = gt << 7;
    }

    __shared__ __align__(16) char smem[32768];

    const int laneg = lane >> 3;
    const int k2sw = ((lane & 7) ^ laneg) << 4;

    int tokq[4];
    if (MODE == 2) {
        #pragma unroll
        for (int qq=0;qq<4;qq++) {
            int t0 = slot_token[slot0 + (w*4+qq)*8 + laneg];
            tokq[qq] = t0 < 0 ? 0 : t0;
        }
    }

    f32x4 acc[4][4];
    #pragma unroll
    for (int m=0;m<4;m++)
        #pragma unroll
        for (int n=0;n<4;n++) acc[m][n] = (f32x4){0.f,0.f,0.f,0.f};

    const int l15 = lane & 15;
    const int l4  = lane >> 4;
    const int wr = w >> 1, wc = w & 1;

    for (int k0 = 0; k0 < K; k0 += 64) {
        __syncthreads();
        #pragma unroll
        for (int qq=0;qq<4;qq++) {
            const char* ga;
            if (MODE == 2) {
                ga = (const char*)A + (((size_t)tokq[qq])*K + k0)*2 + k2sw;
            } else {
                int row = y1row0 + (w*4+qq)*8 + laneg;
                ga = (const char*)A + ((size_t)row*K + k0)*2 + k2sw;
            }
            GLOAD16(ga, smem + (w*4+qq)*1024);
        }
        #pragma unroll
        for (int qq=0;qq<4;qq++) {
            int row = bx*128 + (w*4+qq)*8 + laneg;
            const char* gb = (const char*)Bp + ((size_t)row*K + k0)*2 + k2sw;
            GLOAD16(gb, smem + 16384 + (w*4+qq)*1024);
        }
        __syncthreads();

        short8v a_frag[4][2], b_frag[4][2];
        #pragma unroll
        for (int m=0;m<4;m++) {
            int row = wr*64 + m*16 + l15;
            int rb = row << 7;
            #pragma unroll
            for (int s=0;s<2;s++) {
                int off = rb + ((s*64 + (l4<<4)) ^ ((row&7)<<4));
                a_frag[m][s] = *(const short8v*)(smem + off);
            }
        }
        #pragma unroll
        for (int n=0;n<4;n++) {
            int row = wc*64 + n*16 + l15;
            int rb = row << 7;
            #pragma unroll
            for (int s=0;s<2;s++) {
                int off = rb + ((s*64 + (l4<<4)) ^ ((row&7)<<4));
                b_frag[n][s] = *(const short8v*)(smem + 16384 + off);
            }
        }
        #pragma unroll
        for (int m=0;m<4;m++)
            #pragma unroll
            for (int n=0;n<4;n++) {
                acc[m][n] = __builtin_amdgcn_mfma_f32_16x16x32_bf16(a_frag[m][0], b_frag[n][0], acc[m][n], 0, 0, 0);
                acc[m][n] = __builtin_amdgcn_mfma_f32_16x16x32_bf16(a_frag[m][1], b_frag[n][1], acc[m][n], 0, 0, 0);
            }
    }

    if (MODE == 3) {
        #pragma unroll
        for (int m=0;m<4;m++) {
            #pragma unroll
            for (int j=0;j<4;j++) {
                int orow = wr*64 + m*16 + l4*4 + j;
                int slot = slot0 + orow;
                int tok = slot_token[slot];
                if (tok < 0) continue;
                float sw = slot_w[slot];
                #pragma unroll
                for (int n=0;n<4;n++) {
                    int ocol = bx*128 + wc*64 + n*16 + l15;
                    atomicAdd(&moe_out[(size_t)tok*H_ + ocol], sw * acc[m][n][j]);
                }
            }
        }
    } else {
        __syncthreads();
        #pragma unroll
        for (int m=0;m<4;m++)
            #pragma unroll
            for (int j=0;j<4;j++) {
                int orow = wr*64 + m*16 + l4*4 + j;
                #pragma unroll
                for (int n=0;n<4;n++) {
                    int ocol = wc*64 + n*16 + l15;
                    unsigned short g = f2bf(gelu_fast(acc[m][n][j]));
                    *(unsigned short*)(smem + orow*256 + ocol*2) = g;
                }
            }
        __syncthreads();
        #pragma unroll
        for (int s=0;s<8;s++) {
            int row = w*32 + s*4 + l4;
            short8v v = *(const short8v*)(smem + row*256 + l15*16);
            *(short8v*)((char*)y1 + ((size_t)(y1row0 + row)*N + bx*128 + l15*8)*2) = v;
        }
    }
}

// ---------------- FUSED RoPE+split (blocks <8192) + V transpose+split ----------------
__global__ __launch_bounds__(256) void rope_vsplit(
    const float* __restrict__ qkv,
    __hip_bfloat16* __restrict__ qh, __hip_bfloat16* __restrict__ ql,
    __hip_bfloat16* __restrict__ kh, __hip_bfloat16* __restrict__ kl,
    __hip_bfloat16* __restrict__ vth, __hip_bfloat16* __restrict__ vtl)
{
    __shared__ float t[64][65];
    const int bid = blockIdx.x;
    const int tid = threadIdx.x;
    if (bid < 8192) {
        int idx = bid * 256 + tid;
        int i = idx & 31;
        int n = (idx >> 5) & (NH_-1);
        int tk = idx >> 9;
        int b = tk >> 11;
        int pos = tk & (S_ - 1);
        float inv = exp2f((float)i * (-13.287712379549449f / 32.f));
        float ang = (float)pos * inv;
        float c = cosf(ang), s = sinf(ang);
        size_t base = (size_t)tk*3072 + (size_t)n*64;
        size_t obase = ((size_t)(b*NH_ + n)*S_ + pos)*64;

        float q1 = qkv[base+i], q2 = qkv[base+i+32];
        float qo1 = (q1*c - q2*s)*0.125f;
        float qo2 = (q2*c + q1*s)*0.125f;
        unsigned short h1 = f2bf(qo1), h2 = f2bf(qo2);
        qh[obase+i]    = *(__hip_bfloat16*)&h1;
        qh[obase+i+32] = *(__hip_bfloat16*)&h2;
        unsigned short lo1 = f2bf(qo1 - bf2f(h1)), lo2 = f2bf(qo2 - bf2f(h2));
        ql[obase+i]    = *(__hip_bfloat16*)&lo1;
        ql[obase+i+32] = *(__hip_bfloat16*)&lo2;

        float k1 = qkv[base+1024+i], k2 = qkv[base+1024+i+32];
        float ko1 = k1*c - k2*s;
        float ko2 = k2*c + k1*s;
        unsigned short kh1 = f2bf(ko1), kh2 = f2bf(ko2);
        kh[obase+i]    = *(__hip_bfloat16*)&kh1;
        kh[obase+i+32] = *(__hip_bfloat16*)&kh2;
        unsigned short kl1 = f2bf(ko1 - bf2f(kh1)), kl2 = f2bf(ko2 - bf2f(kh2));
        kl[obase+i]    = *(__hip_bfloat16*)&kl1;
        kl[obase+i+32] = *(__hip_bfloat16*)&kl2;
        return;
    }
    int tt = bid - 8192;           // 1024 blocks: 32 x 16 x 2
    const int s0 = (tt & 31)*64;
    const int hn = (tt >> 5) & 15;
    const int b  = tt >> 9;
    #pragma unroll
    for (int it=0; it<4; ++it) {
        int lin = it*256 + tid;
        int r = lin >> 4, c4 = (lin & 15) << 2;
        float4 vv = *(const float4*)&qkv[(size_t)(b*S_ + s0 + r)*3072 + 2048 + hn*64 + c4];
        t[r][c4] = vv.x; t[r][c4+1] = vv.y; t[r][c4+2] = vv.z; t[r][c4+3] = vv.w;
    }
    __syncthreads();
    size_t obase = (size_t)(b*NH_ + hn)*64*S_;
    #pragma unroll
    for (int it=0; it<4; ++it) {
        int lin = it*256 + tid;
        int d = lin >> 4, c4 = (lin & 15) << 2;
        float v0 = t[c4][d], v1 = t[c4+1][d], v2 = t[c4+2][d], v3 = t[c4+3][d];
        ushort4 hh, ll;
        hh.x = f2bf(v0); hh.y = f2bf(v1); hh.z = f2bf(v2); hh.w = f2bf(v3);
        ll.x = f2bf(v0 - bf2f(hh.x)); ll.y = f2bf(v1 - bf2f(hh.y));
        ll.z = f2bf(v2 - bf2f(hh.z)); ll.w = f2bf(v3 - bf2f(hh.w));
        size_t o = obase + (size_t)d*S_ + s0 + c4;
        *(ushort4*)&vth[o] = hh;
        *(ushort4*)&vtl[o] = ll;
    }
}

// ---------------- MFMA attention: bf16x3, XCD-swizzled, no-max softmax, 32KB LDS,
// 128 q-rows/block ----------------
__global__ __launch_bounds__(256) void attn_mfma(
    const __hip_bfloat16* __restrict__ qh, const __hip_bfloat16* __restrict__ ql,
    const __hip_bfloat16* __restrict__ kh, const __hip_bfloat16* __restrict__ kl,
    const __hip_bfloat16* __restrict__ vth, const __hip_bfloat16* __restrict__ vtl,
    __hip_bfloat16* __restrict__ ctx_hi, __hip_bfloat16* __restrict__ ctx_lo)
{
    const int wg = blockIdx.x;          // 512 blocks
    const int xcd = wg & 7;
    const int ix = wg >> 3;             // 0..63
    const int head = xcd*4 + (ix >> 4); // 4 heads per XCD
    const int qt = ix & 15;             // 16 tiles of 128 q-rows
    const int b = head >> 4, hn = head & 15;

    const int tid = threadIdx.x;
    const int w = tid >> 6, lane = tid & 63;
    const int l15 = lane & 15, l4 = lane >> 4;
    const int laneg = lane >> 3;
    const int k2sw = ((lane & 7) ^ laneg) << 4;

    __shared__ __align__(16) char smem[32768];
    const int KHo = 0, KLo = 8192, VHo = 16384, VLo = 24576;
    const int PHo = 0, PLo = 8192;

    const size_t kbase = (size_t)head*S_*64;
    const size_t vbase = (size_t)head*64*S_;

    short8v qhf[2][2], qlf[2][2];
    #pragma unroll
    for (int m=0;m<2;m++) {
        #pragma unroll
        for (int qq=0;qq<2;qq++) {
            int c = w*2 + qq;
            int row = qt*128 + m*64 + c*8 + laneg;
            size_t off = (kbase + (size_t)row*64)*2 + k2sw;
            GLOAD16((const char*)qh + off, smem + KHo + c*1024);
            GLOAD16((const char*)ql + off, smem + KLo + c*1024);
        }
        __syncthreads();
        {
            int row = w*16 + l15;
            int rsw = (row & 7) << 4;
            #pragma unroll
            for (int s=0;s<2;s++) {
                int off = row*128 + ((s*64 + l4*16) ^ rsw);
                qhf[m][s] = *(const short8v*)(smem + KHo + off);
                qlf[m][s] = *(const short8v*)(smem + KLo + off);
            }
        }
        __syncthreads();
    }

    f32x4 acc[2][4];
    #pragma unroll
    for (int m=0;m<2;m++)
        #pragma unroll
        for (int db=0;db<4;db++) acc[m][db] = (f32x4){0.f,0.f,0.f,0.f};
    float lrun[2][4] = {{0.f,0.f,0.f,0.f},{0.f,0.f,0.f,0.f}};

    for (int kt=0; kt<S_/64; ++kt) {
        #pragma unroll
        for (int qq=0;qq<2;qq++) {
            int c = w*2 + qq;
            int r8 = c*8 + laneg;
            size_t koff = (kbase + (size_t)(kt*64 + r8)*64)*2 + k2sw;
            GLOAD16((const char*)kh + koff, smem + KHo + c*1024);
            GLOAD16((const char*)kl + koff, smem + KLo + c*1024);
            size_t voff = (vbase + (size_t)r8*S_ + kt*64)*2 + k2sw;
            GLOAD16((const char*)vth + voff, smem + VHo + c*1024);
            GLOAD16((const char*)vtl + voff, smem + VLo + c*1024);
        }
        __syncthreads();

        f32x4 s_acc[2][4];
        #pragma unroll
        for (int cb=0;cb<4;cb++) {
            s_acc[0][cb] = (f32x4){0.f,0.f,0.f,0.f};
            s_acc[1][cb] = (f32x4){0.f,0.f,0.f,0.f};
            int row = cb*16 + l15;
            int rsw = (row & 7) << 4;
            #pragma unroll
            for (int s=0;s<2;s++) {
                int off = row*128 + ((s*64 + l4*16) ^ rsw);
                short8v khf = *(const short8v*)(smem + KHo + off);
                short8v klf = *(const short8v*)(smem + KLo + off);
                s_acc[0][cb] = __builtin_amdgcn_mfma_f32_16x16x32_bf16(qhf[0][s], khf, s_acc[0][cb], 0, 0, 0);
                s_acc[0][cb] = __builtin_amdgcn_mfma_f32_16x16x32_bf16(qhf[0][s], klf, s_acc[0][cb], 0, 0, 0);
                s_acc[0][cb] = __builtin_amdgcn_mfma_f32_16x16x32_bf16(qlf[0][s], khf, s_acc[0][cb], 0, 0, 0);
                s_acc[1][cb] = __builtin_amdgcn_mfma_f32_16x16x32_bf16(qhf[1][s], khf, s_acc[1][cb], 0, 0, 0);
                s_acc[1][cb] = __builtin_amdgcn_mfma_f32_16x16x32_bf16(qhf[1][s], klf, s_acc[1][cb], 0, 0, 0);
                s_acc[1][cb] = __builtin_amdgcn_mfma_f32_16x16x32_bf16(qlf[1][s], khf, s_acc[1][cb], 0, 0, 0);
            }
        }
        __syncthreads();

        #pragma unroll
        for (int m=0;m<2;m++) {
            #pragma unroll
            for (int cb=0;cb<4;cb++)
                #pragma unroll
                for (int j=0;j<4;j++) {
                    float p = __expf(s_acc[m][cb][j]);
                    lrun[m][j] += p;
                    int prow = w*16 + l4*4 + j;
                    unsigned short hh = f2bf(p);
                    unsigned short ll = f2bf(p - bf2f(hh));
                    int off = prow*128 + (((cb*16 + l15)*2) ^ ((prow&7)<<4));
                    *(unsigned short*)(smem + PHo + off) = hh;
                    *(unsigned short*)(smem + PLo + off) = ll;
                }
            asm volatile("s_waitcnt lgkmcnt(0)" ::: "memory");
            __builtin_amdgcn_sched_barrier(0);

            short8v pah[2], pal[2];
            {
                int row = w*16 + l15;
                int rsw = (row & 7) << 4;
                #pragma unroll
                for (int s=0;s<2;s++) {
                    int off = row*128 + ((s*64 + l4*16) ^ rsw);
                    pah[s] = *(const short8v*)(smem + PHo + off);
                    pal[s] = *(const short8v*)(smem + PLo + off);
                }
            }
            #pragma unroll
            for (int db=0;db<4;db++) {
                int row = db*16 + l15;
                int rsw = (row & 7) << 4;
                #pragma unroll
                for (int s=0;s<2;s++) {
                    int off = row*128 + ((s*64 + l4*16) ^ rsw);
                    short8v vhf = *(const short8v*)(smem + VHo + off);
                    short8v vlf = *(const short8v*)(smem + VLo + off);
                    acc[m][db] = __builtin_amdgcn_mfma_f32_16x16x32_bf16(pah[s], vhf, acc[m][db], 0, 0, 0);
                    acc[m][db] = __builtin_amdgcn_mfma_f32_16x16x32_bf16(pah[s], vlf, acc[m][db], 0, 0, 0);
                    acc[m][db] = __builtin_amdgcn_mfma_f32_16x16x32_bf16(pal[s], vhf, acc[m][db], 0, 0, 0);
                }
            }
            __builtin_amdgcn_sched_barrier(0);
        }
        __syncthreads();
    }

    #pragma unroll
    for (int m=0;m<2;m++) {
        #pragma unroll
        for (int j=0;j<4;j++) {
            float s = lrun[m][j];
            #pragma unroll
            for (int mk=8;mk;mk>>=1) s += __shfl_xor(s, mk);
            lrun[m][j] = s;
        }
        #pragma unroll
        for (int db=0;db<4;db++)
            #pragma unroll
            for (int j=0;j<4;j++) {
                int qrow = qt*128 + m*64 + w*16 + l4*4 + j;
                float o = acc[m][db][j] / lrun[m][j];
                unsigned short hh = f2bf(o);
                unsigned short ll = f2bf(o - bf2f(hh));
                size_t oidx = (size_t)(b*S_ + qrow)*H_ + hn*64 + db*16 + l15;
                ctx_hi[oidx] = *(__hip_bfloat16*)&hh;
                ctx_lo[oidx] = *(__hip_bfloat16*)&ll;
            }
    }
}

// ---------------- layernorm (residual fused, optional bf16 out, optional fused router) ----------------
template<bool ROUTER>
__global__ __launch_bounds__(256) void ln_kernel(
    const float* __restrict__ a, const float* __restrict__ res,
    const float* __restrict__ g, const float* __restrict__ beta,
    float* __restrict__ out, __hip_bfloat16* __restrict__ outb,
    const float* __restrict__ Wg, int* __restrict__ tok_e,
    float* __restrict__ tok_w, float* __restrict__ P_part)
{
    int row = blockIdx.x, tid = threadIdx.x;
    const float4 va = ((const float4*)(a + (size_t)row*H_))[tid];
    const float4 vr = ((const float4*)(res + (size_t)row*H_))[tid];
    float x0=va.x+vr.x, x1=va.y+vr.y, x2=va.z+vr.z, x3=va.w+vr.w;
    float s  = x0+x1+x2+x3;
    float ss = x0*x0 + x1*x1 + x2*x2 + x3*x3;
    #pragma unroll
    for (int off=32; off; off>>=1) { s += __shfl_xor(s, off); ss += __shfl_xor(ss, off); }
    __shared__ float red[8];
    if ((tid&63)==0) { red[tid>>6]=s; red[4+(tid>>6)]=ss; }
    __syncthreads();
    if (tid==0) { red[0]=red[0]+red[1]+red[2]+red[3]; red[4]=red[4]+red[5]+red[6]+red[7]; }
    __syncthreads();
    float mu  = red[0] * (1.f/H_);
    float var = red[4] * (1.f/H_) - mu*mu;
    float rs = rsqrtf(fmaxf(var, 0.f) + 1e-12f);
    const float4 vg = ((const float4*)g)[tid];
    const float4 vb = ((const float4*)beta)[tid];
    float4 vo;
    vo.x = (x0-mu)*rs*vg.x + vb.x;
    vo.y = (x1-mu)*rs*vg.y + vb.y;
    vo.z = (x2-mu)*rs*vg.z + vb.z;
    vo.w = (x3-mu)*rs*vg.w + vb.w;
    ((float4*)(out + (size_t)row*H_))[tid] = vo;
    if (outb) {
        unsigned int p0 = (unsigned)f2bf(vo.x) | ((unsigned)f2bf(vo.y) << 16);
        unsigned int p1 = (unsigned)f2bf(vo.z) | ((unsigned)f2bf(vo.w) << 16);
        ((uint2*)(outb + (size_t)row*H_))[tid] = make_uint2(p0, p1);
    }
    if (ROUTER) {
        // router logits: this block's token row dot Wg[1024][8]; thread covers cols tid*4..tid*4+3
        float xs0 = vo.x, xs1 = vo.y, xs2 = vo.z, xs3 = vo.w;
        const float4* wg4 = (const float4*)(Wg + (size_t)(tid*4)*E_);
        float pl[E_];
        #pragma unroll
        for (int e=0;e<E_;e++) pl[e] = 0.f;
        #pragma unroll
        for (int r=0;r<4;r++) {
            float xv = (r==0)?xs0:(r==1)?xs1:(r==2)?xs2:xs3;
            float4 wa = wg4[r*2], wb = wg4[r*2+1];
            pl[0] = fmaf(xv, wa.x, pl[0]);
            pl[1] = fmaf(xv, wa.y, pl[1]);
            pl[2] = fmaf(xv, wa.z, pl[2]);
            pl[3] = fmaf(xv, wa.w, pl[3]);
            pl[4] = fmaf(xv, wb.x, pl[4]);
            pl[5] = fmaf(xv, wb.y, pl[5]);
            pl[6] = fmaf(xv, wb.z, pl[6]);
            pl[7] = fmaf(xv, wb.w, pl[7]);
        }
        #pragma unroll
        for (int e=0;e<E_;e++) {
            float v = pl[e];
            #pragma unroll
            for (int off=32; off; off>>=1) v += __shfl_xor(v, off);
            pl[e] = v;
        }
        __shared__ float rr[4][E_];
        if ((tid&63)==0) {
            #pragma unroll
            for (int e=0;e<E_;e++) rr[tid>>6][e] = pl[e];
        }
        __syncthreads();
        if (tid == 0) {
            float lg[E_];
            #pragma unroll
            for (int e=0;e<E_;e++) lg[e] = rr[0][e]+rr[1][e]+rr[2][e]+rr[3][e];
            float mx = lg[0];
            #pragma unroll
            for (int e=1;e<E_;e++) mx = fmaxf(mx, lg[e]);
            float p[E_], se=0.f;
            #pragma unroll
            for (int e=0;e<E_;e++){ p[e] = __expf(lg[e]-mx); se += p[e]; }
            float isv = 1.f/se;
            #pragma unroll
            for (int e=0;e<E_;e++) p[e] *= isv;
            int e1=0;
            #pragma unroll
            for (int e=1;e<E_;e++) if (p[e] > p[e1]) e1=e;
            int e2 = (e1==0)?1:0;
            #pragma unroll
            for (int e=0;e<E_;e++) if (e!=e1 && p[e] > p[e2]) e2=e;
            float w1=p[e1], w2=p[e2], si=1.f/(w1+w2);
            tok_e[row*2]=e1; tok_e[row*2+1]=e2;
            tok_w[row*2]=w1*si; tok_w[row*2+1]=w2*si;
            float4 pa, pb;
            pa.x=p[0]; pa.y=p[1]; pa.z=p[2]; pa.w=p[3];
            pb.x=p[4]; pb.y=p[5]; pb.z=p[6]; pb.w=p[7];
            ((float4*)&P_part[(size_t)row*E_])[0] = pa;
            ((float4*)&P_part[(size_t)row*E_])[1] = pb;
        }
    }
}

// ---------------- router finalize: histogram tok_e + sum P_part (no hot-path atomics) ----------------
__global__ void router_finalize(
    const int* __restrict__ tok_e, const float* __restrict__ P_part,
    int* __restrict__ base, int* __restrict__ cursor,
    int* __restrict__ cnt_pad, int* __restrict__ ntiles,
    int* __restrict__ slot_token, int* __restrict__ tile_expert,
    float* __restrict__ aux_out)
{
    __shared__ int scnt[E_];
    __shared__ float sps[E_];
    __shared__ int sbase[E_+1];
    const int tid = threadIdx.x;
    if (tid < E_) { scnt[tid] = 0; sps[tid] = 0.f; }
    __syncthreads();

    int cnt[E_];
    float ps[E_];
    #pragma unroll
    for (int e=0;e<E_;e++){ cnt[e]=0; ps[e]=0.f; }
    for (int t = tid; t < T_; t += 256) {
        int e1 = tok_e[t*2], e2 = tok_e[t*2+1];
        #pragma unroll
        for (int e=0;e<E_;e++) cnt[e] += (e==e1 ? 1 : 0) + (e==e2 ? 1 : 0);
        float4 a = ((const float4*)&P_part[(size_t)t*E_])[0];
        float4 b = ((const float4*)&P_part[(size_t)t*E_])[1];
        ps[0]+=a.x; ps[1]+=a.y; ps[2]+=a.z; ps[3]+=a.w;
        ps[4]+=b.x; ps[5]+=b.y; ps[6]+=b.z; ps[7]+=b.w;
    }
    #pragma unroll
    for (int e=0;e<E_;e++) {
        int c = cnt[e];
        float v = ps[e];
        #pragma unroll
        for (int off=32; off; off>>=1) { c += __shfl_xor(c, off); v += __shfl_xor(v, off); }
        if ((tid&63)==0) { atomicAdd(&scnt[e], c); atomicAdd(&sps[e], v); }
    }
    __syncthreads();

    if (tid == 0) {
        int bacc = 0;
        float aux = 0.f;
        for (int e=0;e<E_;e++) {
            sbase[e] = bacc; base[e] = bacc;
            int cp = (scnt[e] + 127) & ~127;
            cnt_pad[e] = cp;
            bacc += cp;
            cursor[e] = 0;
            aux += ((float)scnt[e]/(float)T_) * (sps[e]/(float)T_);
        }
        sbase[E_] = bacc;
        *ntiles = bacc >> 7;
        *aux_out = (float)E_ * aux;
    }
    __syncthreads();
    for (int sIdx = tid; sIdx < MAXSLOTS; sIdx += (int)blockDim.x)
        slot_token[sIdx] = -1;
    for (int tt = tid; tt < MAXTILES; tt += (int)blockDim.x) {
        int s = tt*128;
        int e = E_-1;
        for (int qe=0; qe<E_; ++qe) if (s < sbase[qe+1]) { e = qe; break; }
        tile_expert[tt] = e;
    }
}

__global__ void scatter_slots(
    const int* __restrict__ tok_e, const float* __restrict__ tok_w,
    const int* __restrict__ base, int* __restrict__ cursor,
    int* __restrict__ slot_token, float* __restrict__ slot_w)
{
    int t = blockIdx.x*blockDim.x + threadIdx.x;
    if (t >= T_) return;
    #pragma unroll
    for (int j=0;j<2;j++) {
        int e = tok_e[t*2+j];
        int pos = atomicAdd(&cursor[e], 1);
        int s = base[e] + pos;
        slot_token[s] = t;
        slot_w[s] = tok_w[t*2+j];
    }
}

extern "C" void kernel_launch(void* const* d_in, const int* in_sizes, int n_in,
                              void* d_out, int out_size, void* d_ws, size_t ws_size,
                              hipStream_t stream)
{
    const float* x    = (const float*)d_in[0];
    const float* Wq   = (const float*)d_in[1];
    const float* Wk   = (const float*)d_in[2];
    const float* Wv   = (const float*)d_in[3];
    const float* Wd   = (const float*)d_in[4];
    const float* bd   = (const float*)d_in[5];
    const float* ln1g = (const float*)d_in[6];
    const float* ln1b = (const float*)d_in[7];
    const float* Wg   = (const float*)d_in[8];
    const float* W1   = (const float*)d_in[9];
    const float* W2   = (const float*)d_in[10];
    const float* ln2g = (const float*)d_in[11];
    const float* ln2b = (const float*)d_in[12];
    float* out = (float*)d_out;

    float* f0 = (float*)d_ws;
    const size_t M1 = 1u << 20;
    float* qkv      = f0;
    float* attn_out = f0 + 12*M1;
    float* hs       = f0;
    float* moe_out  = f0 + 4*M1;
    float* P_part   = f0 + 8*M1;          // 32K floats in dead qkv region (post-rope)
    __hip_bfloat16* hs_b = (__hip_bfloat16*)(f0 + 16*M1);

    float* misc = f0 + 18*M1;
    int*   misc_i = (int*)misc;
    int*   tok_e   = misc_i;
    float* tok_w   = misc + 8192;
    int*   slot_tok= misc_i + 16384;
    float* slot_w  = misc + 25600;
    int*   cursor  = misc_i + 34832;
    int*   basep   = misc_i + 34840;
    int*   cnt_pad = misc_i + 34848;
    int*   ntiles  = misc_i + 34856;
    int*   tile_ex = misc_i + 34857;

    float* off_p = f0 + 18*M1 + 65536;
    __hip_bfloat16* xa_hi = (__hip_bfloat16*)(off_p);
    __hip_bfloat16* xa_lo = (__hip_bfloat16*)(off_p + 2*M1);
    __hip_bfloat16* at_qh = (__hip_bfloat16*)(off_p + 4*M1);
    __hip_bfloat16* at_ql = (__hip_bfloat16*)(off_p + 6*M1);
    __hip_bfloat16* at_kh = (__hip_bfloat16*)(off_p + 8*M1);
    __hip_bfloat16* at_kl = (__hip_bfloat16*)(off_p + 10*M1);
    __hip_bfloat16* at_vh = (__hip_bfloat16*)(off_p + 12*M1);
    __hip_bfloat16* at_vl = (__hip_bfloat16*)(off_p + 14*M1);
    __hip_bfloat16* wqkv_h = (__hip_bfloat16*)(off_p + 16*M1);
    __hip_bfloat16* wqkv_l = (__hip_bfloat16*)(off_p + 16*M1 + 3*(M1/2));
    __hip_bfloat16* wd_h = (__hip_bfloat16*)(off_p + 19*M1);
    __hip_bfloat16* wd_l = (__hip_bfloat16*)(off_p + 19*M1 + M1/2);

    const bool FULL = ws_size >= (size_t)300*1024*1024;
    // FULL layout: W1t @ +20M1 (16M1 span), W2t @ +36M1 (16M1 span).
    // y1F overlays off_p+0 .. +18.875M1 (xa + at_* + wqkv — all dead by MoE time).
    __hip_bfloat16* W1t = (__hip_bfloat16*)(off_p + 20*M1);
    __hip_bfloat16* W2t = (__hip_bfloat16*)(off_p + 36*M1);
    __hip_bfloat16* y1F = (__hip_bfloat16*)(off_p);
    float* wreg = off_p + 4*M1;   // PE path scratch

    dim3 blk(256);

    prep_inputs<<<dim3(5120), blk, 0, stream>>>(x, Wq, Wk, Wv, Wd, xa_hi, xa_lo, wqkv_h, wqkv_l, wd_h, wd_l);

    if (FULL) {
        fused_qkv_w12<<<dim3(768 + 8192 + 8192), blk, 0, stream>>>(
            xa_hi, xa_lo, wqkv_h, wqkv_l, qkv, W1, W2, W1t, W2t);
    } else {
        fused_qkv_w12<<<dim3(768), blk, 0, stream>>>(
            xa_hi, xa_lo, wqkv_h, wqkv_l, qkv, nullptr, nullptr, nullptr, nullptr);
    }

    rope_vsplit<<<dim3(8192 + 1024), blk, 0, stream>>>(qkv, at_qh, at_ql, at_kh, at_kl, at_vh, at_vl);

    attn_mfma<<<dim3(B_*NH_*(S_/128)), blk, 0, stream>>>(at_qh, at_ql, at_kh, at_kl, at_vh, at_vl, xa_hi, xa_lo);

    // attn_out = ctx@Wd + bd, fused with moe_out/misc zeroing
    wd_gemm_zero<<<dim3(256 + 4096), blk, 0, stream>>>(xa_hi, xa_lo, wd_h, wd_l, attn_out, bd, moe_out, misc + 34816);

    // ln1 + fused router (tok_e/tok_w/P_part per token; no global atomics)
    ln_kernel<true><<<T_, blk, 0, stream>>>(attn_out, x, ln1g, ln1b, hs, hs_b,
                                            Wg, tok_e, tok_w, P_part);

    router_finalize<<<1, blk, 0, stream>>>(tok_e, P_part, basep, cursor, cnt_pad, ntiles,
                                           slot_tok, tile_ex, out + (size_t)T_*H_);
    scatter_slots<<<T_/256, blk, 0, stream>>>(tok_e, tok_w, basep, cursor, slot_tok, slot_w);

    if (FULL) {
        moe_mfma<2,false><<<dim3(MAXTILES*32), blk, 0, stream>>>(
            hs_b, W1t, y1F, nullptr, slot_tok, slot_w, tile_ex, ntiles, nullptr, I_, H_, 32);
        moe_mfma<3,false><<<dim3(MAXTILES*8), blk, 0, stream>>>(
            y1F, W2t, nullptr, moe_out, slot_tok, slot_w, tile_ex, ntiles, nullptr, H_, I_, 8);
    } else {
        __hip_bfloat16* w1t = (__hip_bfloat16*)wreg;
        __hip_bfloat16* w2t = (__hip_bfloat16*)(wreg + 2*M1);
        __hip_bfloat16* y1  = (__hip_bfloat16*)(wreg + 4*M1);
        for (int e=0; e<E_; ++e) {
            transpose_bf16<<<dim3(I_/64, H_/64, 1), blk, 0, stream>>>(W1 + (size_t)e*H_*I_, w1t, H_, I_);
            moe_mfma<2,true><<<dim3(I_/128, 32), blk, 0, stream>>>(
                hs_b, w1t, y1, nullptr, slot_tok, slot_w, nullptr, cnt_pad+e, basep+e, I_, H_, 0);
            transpose_bf16<<<dim3(H_/64, I_/64, 1), blk, 0, stream>>>(W2 + (size_t)e*I_*H_, w2t, I_, H_);
            moe_mfma<3,true><<<dim3(H_/128, 32), blk, 0, stream>>>(
                y1, w2t, nullptr, moe_out, slot_tok, slot_w, nullptr, cnt_pad+e, basep+e, H_, I_, 0);
        }
    }

    ln_kernel<false><<<T_, blk, 0, stream>>>(moe_out, hs, ln2g, ln2b, out, nullptr,
                                             nullptr, nullptr, nullptr, nullptr);
}